// Round 7
// baseline (411.542 us; speedup 1.0000x reference)
//
#include <hip/hip_runtime.h>

// GCN 2-layer fused:  out = relu( A·(A·x)·(W1@W2) + (A·1)⊗(b1ᵀW2) + b2 )
// A = D^-1/2 (Adj + I) D^-1/2.  Both aggregation passes gather int16 rows
// (per-row dynamic scale). Direct per-lane index gather (no cross-lane shfl
// in the inner loop). CSR built either as padded csr2d (fused rank+fill,
// needs more ws) or compact csr via rank/scan/fill (fallback) — chosen by
// ws_size, deterministic.

#define WS_ALIGN(x) (((x) + 255) & ~(size_t)255)
#define MAXDEG 48

typedef float v2f __attribute__((ext_vector_type(2)));

__global__ void k_init_deg(int* __restrict__ deg, int N) {
    int i = blockIdx.x * blockDim.x + threadIdx.x;
    if (i < N) deg[i] = 0;   // real edges only; self-loop added in dinv
}

// Fused degree + padded-CSR fill (big-ws path).
__global__ void k_rankfill(const int* __restrict__ src, const int* __restrict__ dst,
                           int* __restrict__ deg, int* __restrict__ csr2d, int E, int N) {
    int tid = blockIdx.x * blockDim.x + threadIdx.x;
    int stride = gridDim.x * blockDim.x;
#pragma unroll
    for (int it = 0; it < 8; ++it) {
        int e = tid + it * stride;
        if (e < E) {
            int d = dst[e];
            int s = src[e];
            if ((unsigned)d < (unsigned)N && (unsigned)s < (unsigned)N) {
                int slot = atomicAdd(&deg[d], 1);
                if (slot < MAXDEG) csr2d[d * MAXDEG + slot] = s;
            }
        }
    }
}

// --- fallback (compact csr) path kernels ---
__global__ void k_rank(const int* __restrict__ dst, int* __restrict__ deg,
                       int* __restrict__ rank, int E, int N) {
    int tid = blockIdx.x * blockDim.x + threadIdx.x;
    int stride = gridDim.x * blockDim.x;
#pragma unroll
    for (int it = 0; it < 8; ++it) {
        int e = tid + it * stride;
        if (e < E) {
            int d = dst[e];
            if ((unsigned)d < (unsigned)N) rank[e] = atomicAdd(&deg[d], 1);
        }
    }
}

__global__ void k_scan1(const int* __restrict__ deg, int* __restrict__ offs,
                        int* __restrict__ bsums, int N) {
    __shared__ int sh[256];
    int i = blockIdx.x * 256 + threadIdx.x;
    int v = (i < N) ? deg[i] : 0;
    sh[threadIdx.x] = v;
    __syncthreads();
    for (int off = 1; off < 256; off <<= 1) {
        int t = (threadIdx.x >= off) ? sh[threadIdx.x - off] : 0;
        __syncthreads();
        sh[threadIdx.x] += t;
        __syncthreads();
    }
    if (i < N) offs[i] = sh[threadIdx.x] - v;
    if (threadIdx.x == 255) bsums[blockIdx.x] = sh[255];
}

__global__ void k_scan2(int* __restrict__ bsums, int nb) {
    __shared__ int sh[512];
    int tid = threadIdx.x;
    int v = (tid < nb) ? bsums[tid] : 0;
    sh[tid] = v;
    __syncthreads();
    for (int off = 1; off < 512; off <<= 1) {
        int t = (tid >= off) ? sh[tid - off] : 0;
        __syncthreads();
        sh[tid] += t;
        __syncthreads();
    }
    if (tid < nb) bsums[tid] = sh[tid] - v;
}

__global__ void k_scan3(int* __restrict__ offs, const int* __restrict__ bsums, int N, int E) {
    int i = blockIdx.x * 256 + threadIdx.x;
    if (i < N) offs[i] += bsums[blockIdx.x];
    if (blockIdx.x == 0 && threadIdx.x == 0) offs[N] = E;
}

__global__ void k_fill(const int* __restrict__ src, const int* __restrict__ dst,
                       const int* __restrict__ rank, const int* __restrict__ offs,
                       int* __restrict__ csr, int E, int N) {
    int tid = blockIdx.x * blockDim.x + threadIdx.x;
    int stride = gridDim.x * blockDim.x;
#pragma unroll
    for (int it = 0; it < 8; ++it) {
        int e = tid + it * stride;
        if (e < E) {
            int d = dst[e];
            int s = src[e];
            int r = rank[e];
            if ((unsigned)d < (unsigned)N && (unsigned)s < (unsigned)N)
                csr[offs[d] + r] = s;
        }
    }
}
// --- end fallback kernels ---

__global__ void k_dinv(const int* __restrict__ deg, float* __restrict__ dinv, int N) {
    int i = blockIdx.x * blockDim.x + threadIdx.x;
    if (i < N) dinv[i] = rsqrtf((float)(deg[i] + 1));
}

// x (f32) -> int16 with per-row scale. One wave per row; lane owns 2 elems.
// meta[i] = (dinv[i], dinv[i]*scale[i]) -> the fused gather weight.
__launch_bounds__(256)
__global__ void k_toq16(const float* __restrict__ x, const float* __restrict__ dinv,
                        ushort* __restrict__ xq, float2* __restrict__ meta, int N) {
    int gw = (int)((blockIdx.x * (size_t)blockDim.x + threadIdx.x) >> 6);
    int lane = threadIdx.x & 63;
    if (gw >= N) return;
    float2 v = ((const float2*)(x + (size_t)gw * 128))[lane];
    float m = fmaxf(fabsf(v.x), fabsf(v.y));
#pragma unroll
    for (int d = 1; d < 64; d <<= 1) m = fmaxf(m, __shfl_xor(m, d));
    float inv = (m > 0.f) ? 32767.f / m : 0.f;
    int qa = __float2int_rn(v.x * inv);
    int qb = __float2int_rn(v.y * inv);
    uint packed = ((uint)qa & 0xFFFFu) | ((uint)qb << 16);
    ((uint*)xq)[(size_t)gw * 64 + lane] = packed;
    if (lane == 0) {
        float di = dinv[gw];
        meta[gw] = make_float2(di, di * (m * (1.f / 32767.f)));
    }
}

__device__ inline v2f unpack2(uint p) {
    v2f f;
    f.x = (float)(short)(p & 0xFFFFu);
    f.y = (float)((int)p >> 16);
    return f;
}

// Aggregation over int16 rows, direct gather. One wave per node; quarter q
// owns edge t = 4i+q, its 16 lanes (ql) load the 256B row as uint4.
// idx loads: 16 lanes share an address (HW broadcast), L1-hot line.
// No cross-lane ops inside the divergent guard.
template <int WRITE_Q>
__launch_bounds__(256)
__global__ void k_aggq(const ushort* __restrict__ xq, const float2* __restrict__ meta,
                       float* __restrict__ fout,
                       ushort* __restrict__ qout, float2* __restrict__ mout,
                       float* __restrict__ svec,
                       const int* __restrict__ offs, const int* __restrict__ deg,
                       const int* __restrict__ csr, int stride2d, int N) {
    int gw = (int)((blockIdx.x * (size_t)blockDim.x + threadIdx.x) >> 6);
    int lane = threadIdx.x & 63;
    if (gw >= N) return;
    int q = lane >> 4, ql = lane & 15;
    float2 ms = meta[gw];
    float di = ms.x;
    const uint4* __restrict__ xq4 = (const uint4*)xq;

    v2f acc[4];
#pragma unroll
    for (int j = 0; j < 4; ++j) acc[j] = (v2f)(0.f);
    float wsum = 0.f;

    if (q == 0) {  // self term: weight di*scale_self = ms.y
        uint4 v = xq4[((unsigned)gw << 4) + ql];
        v2f d2 = {ms.y, ms.y};
        acc[0] = d2 * unpack2(v.x);
        acc[1] = d2 * unpack2(v.y);
        acc[2] = d2 * unpack2(v.z);
        acc[3] = d2 * unpack2(v.w);
    }

    int dg = deg[gw];
    int base, dgc;
    if (stride2d) {
        base = gw * stride2d;
        dgc = min(dg, stride2d);
    } else {
        base = offs[gw];
        dgc = dg;
    }
    int iters = (dgc + 3) >> 2;
#pragma unroll 4
    for (int i = 0; i < iters; ++i) {
        int t = 4 * i + q;
        if (t < dgc) {
            int sidx = csr[base + t];
            float2 mm = meta[sidx];
            uint4 v = xq4[((unsigned)sidx << 4) + ql];
            v2f d2 = {mm.y, mm.y};
            acc[0] = __builtin_elementwise_fma(d2, unpack2(v.x), acc[0]);
            acc[1] = __builtin_elementwise_fma(d2, unpack2(v.y), acc[1]);
            acc[2] = __builtin_elementwise_fma(d2, unpack2(v.z), acc[2]);
            acc[3] = __builtin_elementwise_fma(d2, unpack2(v.w), acc[3]);
            wsum += mm.x;   // identical within the q-group; one group per edge
        }
    }

    // combine 4 quarters (same feature slice in each): every lane ends with
    // the full slice sum. wsum: groups hold identical copies -> xor16+xor32
    // sums exactly one copy per group.
#pragma unroll
    for (int j = 0; j < 4; ++j) {
        acc[j].x += __shfl_xor(acc[j].x, 16);
        acc[j].y += __shfl_xor(acc[j].y, 16);
        acc[j].x += __shfl_xor(acc[j].x, 32);
        acc[j].y += __shfl_xor(acc[j].y, 32);
        acc[j] *= di;
    }
    wsum += __shfl_xor(wsum, 16);
    wsum += __shfl_xor(wsum, 32);

    if (WRITE_Q) {
        if (lane == 0) svec[gw] = di * (di + wsum);
        float m = 0.f;
#pragma unroll
        for (int j = 0; j < 4; ++j) m = fmaxf(m, fmaxf(fabsf(acc[j].x), fabsf(acc[j].y)));
#pragma unroll
        for (int d = 1; d < 16; d <<= 1) m = fmaxf(m, __shfl_xor(m, d));
        float inv = (m > 0.f) ? 32767.f / m : 0.f;
        if (q == 0) {
            uint4 o;
            int q0 = __float2int_rn(acc[0].x * inv), q1 = __float2int_rn(acc[0].y * inv);
            int q2 = __float2int_rn(acc[1].x * inv), q3 = __float2int_rn(acc[1].y * inv);
            int q4 = __float2int_rn(acc[2].x * inv), q5 = __float2int_rn(acc[2].y * inv);
            int q6 = __float2int_rn(acc[3].x * inv), q7 = __float2int_rn(acc[3].y * inv);
            o.x = ((uint)q0 & 0xFFFFu) | ((uint)q1 << 16);
            o.y = ((uint)q2 & 0xFFFFu) | ((uint)q3 << 16);
            o.z = ((uint)q4 & 0xFFFFu) | ((uint)q5 << 16);
            o.w = ((uint)q6 & 0xFFFFu) | ((uint)q7 << 16);
            *(uint4*)(qout + (size_t)gw * 128 + ql * 8) = o;
        }
        if (lane == 0) mout[gw] = make_float2(di, di * (m * (1.f / 32767.f)));
    } else {
        if (q == 0) {
            float4 o0, o1;
            o0.x = acc[0].x; o0.y = acc[0].y; o0.z = acc[1].x; o0.w = acc[1].y;
            o1.x = acc[2].x; o1.y = acc[2].y; o1.z = acc[3].x; o1.w = acc[3].y;
            *(float4*)(fout + (size_t)gw * 128 + ql * 8) = o0;
            *(float4*)(fout + (size_t)gw * 128 + ql * 8 + 4) = o1;
        }
    }
}

// W12 = W1 @ W2  (128x128 @ 128x128), one output per thread.
__global__ void k_w12(const float* __restrict__ W1, const float* __restrict__ W2,
                      float* __restrict__ w12) {
    int idx = blockIdx.x * 256 + threadIdx.x;  // 0..16383
    int i = idx >> 7, j = idx & 127;
    float s = 0.f;
#pragma unroll 8
    for (int k = 0; k < 128; ++k) s = fmaf(W1[i * 128 + k], W2[k * 128 + j], s);
    w12[idx] = s;
}

// cvec = b1^T @ W2  (128,)
__global__ void k_cvec(const float* __restrict__ b1, const float* __restrict__ W2,
                       float* __restrict__ cvec) {
    int j = threadIdx.x;
    float s = 0.f;
#pragma unroll 8
    for (int k = 0; k < 128; ++k) s = fmaf(b1[k], W2[k * 128 + j], s);
    cvec[j] = s;
}

// out = relu( X @ W12 + svec ⊗ cvec + b2 ) — fp32 vector GEMM, LDS-tiled.
// 512 threads / 128 rows per block; ws 64KB + xs 64KB LDS (2 waves/SIMD).
// Safe in-place (X == out).
__launch_bounds__(512)
__global__ void k_gemm(const float* __restrict__ X, const float* __restrict__ Wg,
                       const float* __restrict__ svec, const float* __restrict__ cvec,
                       const float* __restrict__ b2, float* __restrict__ out, int N) {
    __shared__ float ws[128 * 128];
    __shared__ float xs[128 * 128];
    int tid = threadIdx.x;
    int row0 = blockIdx.x * 128;

    {
        const float4* srcv = (const float4*)Wg;
        float4* dstv = (float4*)ws;
#pragma unroll
        for (int it = 0; it < 8; ++it) dstv[it * 512 + tid] = srcv[it * 512 + tid];
    }
#pragma unroll
    for (int it = 0; it < 8; ++it) {
        int idx = it * 512 + tid;
        int r = idx >> 5, cg = idx & 31;
        int grow = row0 + r;
        float4 v = make_float4(0.f, 0.f, 0.f, 0.f);
        if (grow < N) v = *(const float4*)(X + (size_t)grow * 128 + cg * 4);
        int c0 = (cg * 4) ^ ((r & 7) << 2);
        *(float4*)&xs[r * 128 + c0] = v;
    }
    __syncthreads();

    int ty = tid >> 4, tx = tid & 15;
    int r0 = ty * 4;
    float acc0[4][4] = {{0.f}};
    float acc1[4][4] = {{0.f}};

#pragma unroll 2
    for (int k0 = 0; k0 < 128; k0 += 4) {
        float4 w0[4], w1[4];
#pragma unroll
        for (int kk = 0; kk < 4; ++kk) {
            w0[kk] = *(const float4*)&ws[(k0 + kk) * 128 + 4 * tx];
            w1[kk] = *(const float4*)&ws[(k0 + kk) * 128 + 64 + 4 * tx];
        }
#pragma unroll
        for (int j = 0; j < 4; ++j) {
            int r = r0 + j;
            float4 a = *(const float4*)&xs[r * 128 + (k0 ^ ((r & 7) << 2))];
            float av[4] = {a.x, a.y, a.z, a.w};
#pragma unroll
            for (int kk = 0; kk < 4; ++kk) {
                acc0[j][0] = fmaf(av[kk], w0[kk].x, acc0[j][0]);
                acc0[j][1] = fmaf(av[kk], w0[kk].y, acc0[j][1]);
                acc0[j][2] = fmaf(av[kk], w0[kk].z, acc0[j][2]);
                acc0[j][3] = fmaf(av[kk], w0[kk].w, acc0[j][3]);
                acc1[j][0] = fmaf(av[kk], w1[kk].x, acc1[j][0]);
                acc1[j][1] = fmaf(av[kk], w1[kk].y, acc1[j][1]);
                acc1[j][2] = fmaf(av[kk], w1[kk].z, acc1[j][2]);
                acc1[j][3] = fmaf(av[kk], w1[kk].w, acc1[j][3]);
            }
        }
    }

    float c0v[4], c1v[4], b0v[4], b1v[4];
#pragma unroll
    for (int m = 0; m < 4; ++m) {
        c0v[m] = cvec[4 * tx + m];
        c1v[m] = cvec[64 + 4 * tx + m];
        b0v[m] = b2[4 * tx + m];
        b1v[m] = b2[64 + 4 * tx + m];
    }
#pragma unroll
    for (int j = 0; j < 4; ++j) {
        int grow = row0 + r0 + j;
        if (grow >= N) continue;
        float sv = svec[grow];
        float4 o0, o1;
        o0.x = fmaxf(acc0[j][0] + sv * c0v[0] + b0v[0], 0.f);
        o0.y = fmaxf(acc0[j][1] + sv * c0v[1] + b0v[1], 0.f);
        o0.z = fmaxf(acc0[j][2] + sv * c0v[2] + b0v[2], 0.f);
        o0.w = fmaxf(acc0[j][3] + sv * c0v[3] + b0v[3], 0.f);
        o1.x = fmaxf(acc1[j][0] + sv * c1v[0] + b1v[0], 0.f);
        o1.y = fmaxf(acc1[j][1] + sv * c1v[1] + b1v[1], 0.f);
        o1.z = fmaxf(acc1[j][2] + sv * c1v[2] + b1v[2], 0.f);
        o1.w = fmaxf(acc1[j][3] + sv * c1v[3] + b1v[3], 0.f);
        *(float4*)&out[(size_t)grow * 128 + 4 * tx] = o0;
        *(float4*)&out[(size_t)grow * 128 + 64 + 4 * tx] = o1;
    }
}

extern "C" void kernel_launch(void* const* d_in, const int* in_sizes, int n_in,
                              void* d_out, int out_size, void* d_ws, size_t ws_size,
                              hipStream_t stream) {
    const float* x  = (const float*)d_in[0];
    const int*   ei = (const int*)d_in[1];
    const float* W1 = (const float*)d_in[2];
    const float* b1 = (const float*)d_in[3];
    const float* W2 = (const float*)d_in[4];
    const float* b2 = (const float*)d_in[5];
    float* out = (float*)d_out;

    int N = in_sizes[0] / 128;
    int E = in_sizes[1] / 2;
    const int* srcE = ei;
    const int* dstE = ei + E;

    char* w = (char*)d_ws;
    size_t off = 0;
    auto alloc = [&](size_t bytes) {
        void* p = w + off;
        off = WS_ALIGN(off + bytes);
        return p;
    };
    ushort* xq    = (ushort*)alloc((size_t)N * 256);
    ushort* t1q   = (ushort*)alloc((size_t)N * 256);   // fallback: rank lives here early
    float2* meta1 = (float2*)alloc((size_t)N * 8);
    float2* meta2 = (float2*)alloc((size_t)N * 8);
    int*   deg    = (int*)alloc((size_t)N * 4);
    int*   offs   = (int*)alloc((size_t)(N + 1) * 4);
    int*   bsums  = (int*)alloc(4096);
    float* dinv   = (float*)alloc((size_t)N * 4);
    float* svec   = (float*)alloc((size_t)N * 4);
    float* w12    = (float*)alloc(128 * 128 * 4);
    float* cvec   = (float*)alloc(128 * 4);
    size_t common = off;
    (void)n_in; (void)out_size;

    size_t need_big = common + WS_ALIGN((size_t)N * MAXDEG * 4);
    bool big = (ws_size >= need_big);

    int nb = (N + 255) / 256;
    int eb8 = (E + 8 * 256 - 1) / (8 * 256);

    k_init_deg<<<(N + 255) / 256, 256, 0, stream>>>(deg, N);

    const int* csr_use;
    int stride2d;
    if (big) {
        int* csr2d = (int*)alloc((size_t)N * MAXDEG * 4);
        k_rankfill<<<eb8, 256, 0, stream>>>(srcE, dstE, deg, csr2d, E, N);
        k_dinv<<<(N + 255) / 256, 256, 0, stream>>>(deg, dinv, N);
        csr_use = csr2d;
        stride2d = MAXDEG;
    } else {
        int* csr  = (int*)alloc((size_t)E * 4);
        int* rank = (int*)t1q;  // dead before t1q is written
        k_rank<<<eb8, 256, 0, stream>>>(dstE, deg, rank, E, N);
        k_dinv<<<(N + 255) / 256, 256, 0, stream>>>(deg, dinv, N);
        k_scan1<<<nb, 256, 0, stream>>>(deg, offs, bsums, N);
        k_scan2<<<1, 512, 0, stream>>>(bsums, nb);
        k_scan3<<<nb, 256, 0, stream>>>(offs, bsums, N, E);
        k_fill<<<eb8, 256, 0, stream>>>(srcE, dstE, rank, offs, csr, E, N);
        csr_use = csr;
        stride2d = 0;
    }

    k_toq16<<<(N + 3) / 4, 256, 0, stream>>>(x, dinv, xq, meta1, N);
    // pass 1: t1 = A x   (int16 in, int16 out) + svec
    k_aggq<1><<<(N + 3) / 4, 256, 0, stream>>>(xq, meta1, nullptr, t1q, meta2, svec,
                                               offs, deg, csr_use, stride2d, N);
    // pass 2: t2 = A t1  (int16 in, f32 out -> d_out as scratch)
    k_aggq<0><<<(N + 3) / 4, 256, 0, stream>>>(t1q, meta2, out, nullptr, nullptr, nullptr,
                                               offs, deg, csr_use, stride2d, N);
    k_w12<<<64, 256, 0, stream>>>(W1, W2, w12);
    k_cvec<<<1, 128, 0, stream>>>(b1, W2, cvec);
    // out = relu(t2 @ W12 + svec ⊗ cvec + b2), in-place on d_out
    k_gemm<<<(N + 127) / 128, 512, 0, stream>>>(out, w12, svec, cvec, b2, out, N);
}

// Round 8
// 358.877 us; speedup vs baseline: 1.1467x; 1.1467x over previous
//
#include <hip/hip_runtime.h>

// GCN 2-layer fused:  out = relu( A·(A·x)·(W1@W2) + (A·1)⊗(b1ᵀW2) + b2 )
// A = D^-1/2 (Adj + I) D^-1/2.  Both aggregation passes gather int16 rows
// with per-row dynamic scale. Pass 2 writes f32 into d_out; GEMM in-place.
// All __shfl executed unconditionally (ds_bpermute from an exec-masked lane
// is undefined). CSR built via split rank/scan/fill (decoupled atomic chain).

#define WS_ALIGN(x) (((x) + 255) & ~(size_t)255)

__global__ void k_init_deg(int* __restrict__ deg, int N) {
    int i = blockIdx.x * blockDim.x + threadIdx.x;
    if (i < N) deg[i] = 0;   // real edges only; self-loop added in dinv
}

// degree count + within-segment rank (atomicAdd return). rank write coalesced.
__global__ void k_rank(const int* __restrict__ dst, int* __restrict__ deg,
                       int* __restrict__ rank, int E, int N) {
    int tid = blockIdx.x * blockDim.x + threadIdx.x;
    int stride = gridDim.x * blockDim.x;
#pragma unroll
    for (int it = 0; it < 8; ++it) {
        int e = tid + it * stride;
        if (e < E) {
            int d = dst[e];
            if ((unsigned)d < (unsigned)N) rank[e] = atomicAdd(&deg[d], 1);
        }
    }
}

__global__ void k_dinv(const int* __restrict__ deg, float* __restrict__ dinv, int N) {
    int i = blockIdx.x * blockDim.x + threadIdx.x;
    if (i < N) dinv[i] = rsqrtf((float)(deg[i] + 1));
}

// Block-local exclusive scan of deg (256/block), emits block sums.
__global__ void k_scan1(const int* __restrict__ deg, int* __restrict__ offs,
                        int* __restrict__ bsums, int N) {
    __shared__ int sh[256];
    int i = blockIdx.x * 256 + threadIdx.x;
    int v = (i < N) ? deg[i] : 0;
    sh[threadIdx.x] = v;
    __syncthreads();
    for (int off = 1; off < 256; off <<= 1) {
        int t = (threadIdx.x >= off) ? sh[threadIdx.x - off] : 0;
        __syncthreads();
        sh[threadIdx.x] += t;
        __syncthreads();
    }
    if (i < N) offs[i] = sh[threadIdx.x] - v;
    if (threadIdx.x == 255) bsums[blockIdx.x] = sh[255];
}

// Exclusive scan of up to 512 block sums in one block.
__global__ void k_scan2(int* __restrict__ bsums, int nb) {
    __shared__ int sh[512];
    int tid = threadIdx.x;
    int v = (tid < nb) ? bsums[tid] : 0;
    sh[tid] = v;
    __syncthreads();
    for (int off = 1; off < 512; off <<= 1) {
        int t = (tid >= off) ? sh[tid - off] : 0;
        __syncthreads();
        sh[tid] += t;
        __syncthreads();
    }
    if (tid < nb) bsums[tid] = sh[tid] - v;
}

__global__ void k_scan3(int* __restrict__ offs, const int* __restrict__ bsums, int N, int E) {
    int i = blockIdx.x * 256 + threadIdx.x;
    if (i < N) offs[i] += bsums[blockIdx.x];
    if (blockIdx.x == 0 && threadIdx.x == 0) offs[N] = E;
}

// Atomic-free CSR fill: slot = offs[dst] + rank. Fire-and-forget scatter.
__global__ void k_fill(const int* __restrict__ src, const int* __restrict__ dst,
                       const int* __restrict__ rank, const int* __restrict__ offs,
                       int* __restrict__ csr, int E, int N) {
    int tid = blockIdx.x * blockDim.x + threadIdx.x;
    int stride = gridDim.x * blockDim.x;
#pragma unroll
    for (int it = 0; it < 8; ++it) {
        int e = tid + it * stride;
        if (e < E) {
            int d = dst[e];
            int s = src[e];
            int r = rank[e];
            if ((unsigned)d < (unsigned)N && (unsigned)s < (unsigned)N)
                csr[offs[d] + r] = s;
        }
    }
}

// x (f32) -> int16 with per-row scale. One wave per row; lane owns 2 elems.
// meta[i] = (dinv[i], dinv[i]*scale[i]) -> the fused gather weight.
__launch_bounds__(256)
__global__ void k_toq16(const float* __restrict__ x, const float* __restrict__ dinv,
                        ushort* __restrict__ xq, float2* __restrict__ meta, int N) {
    int gw = (int)((blockIdx.x * (size_t)blockDim.x + threadIdx.x) >> 6);
    int lane = threadIdx.x & 63;
    if (gw >= N) return;
    float2 v = ((const float2*)(x + (size_t)gw * 128))[lane];
    float m = fmaxf(fabsf(v.x), fabsf(v.y));
#pragma unroll
    for (int d = 1; d < 64; d <<= 1) m = fmaxf(m, __shfl_xor(m, d));
    float inv = (m > 0.f) ? 32767.f / m : 0.f;
    int qa = __float2int_rn(v.x * inv);
    int qb = __float2int_rn(v.y * inv);
    uint packed = ((uint)qa & 0xFFFFu) | ((uint)qb << 16);
    ((uint*)xq)[(size_t)gw * 64 + lane] = packed;
    if (lane == 0) {
        float di = dinv[gw];
        meta[gw] = make_float2(di, di * (m * (1.f / 32767.f)));
    }
}

__device__ inline void unpackq(uint4 v, float f[8]) {
    f[0] = (float)(short)(v.x & 0xFFFFu);
    f[1] = (float)((int)v.x >> 16);
    f[2] = (float)(short)(v.y & 0xFFFFu);
    f[3] = (float)((int)v.y >> 16);
    f[4] = (float)(short)(v.z & 0xFFFFu);
    f[5] = (float)((int)v.z >> 16);
    f[6] = (float)(short)(v.w & 0xFFFFu);
    f[7] = (float)((int)v.w >> 16);
}

// Aggregation over int16 rows (round-6 proven structure). One wave per node;
// quarter-wave (16 lanes) covers a 256B int16 row via uint4 -> 4 neighbor
// rows in flight/iteration. csr/meta loaded once per 64-edge chunk (1-deep
// gather chain per iteration; edge params distributed via bpermute).
template <int WRITE_Q>
__launch_bounds__(256)
__global__ void k_aggq(const ushort* __restrict__ xq, const float2* __restrict__ meta,
                       float* __restrict__ fout,
                       ushort* __restrict__ qout, float2* __restrict__ mout,
                       float* __restrict__ svec,
                       const int* __restrict__ offs, const int* __restrict__ csr, int N) {
    int gw = (int)((blockIdx.x * (size_t)blockDim.x + threadIdx.x) >> 6);
    int lane = threadIdx.x & 63;
    if (gw >= N) return;
    int q = lane >> 4, ql = lane & 15;
    float2 ms = meta[gw];
    float di = ms.x;

    float acc[8];
#pragma unroll
    for (int j = 0; j < 8; ++j) acc[j] = 0.f;
    float ssum = (lane == 0) ? di : 0.f;

    if (q == 0) {  // self term: weight di*scale_self = ms.y
        uint4 v = *(const uint4*)(xq + (size_t)gw * 128 + ql * 8);
        float f[8];
        unpackq(v, f);
#pragma unroll
        for (int j = 0; j < 8; ++j) acc[j] = ms.y * f[j];
    }

    int s0 = offs[gw], s1 = offs[gw + 1];
    for (int base = s0; base < s1; base += 64) {
        int cnt = min(64, s1 - base);
        int sidx = 0;
        float wv = 0.f, dv = 0.f;   // lanes >= cnt keep 0 -> d==0 for padded t
        if (lane < cnt) {
            sidx = csr[base + lane];
            float2 mm = meta[sidx];
            dv = mm.x;
            wv = mm.y;
        }
        int iters = (cnt + 3) >> 2;
#pragma unroll 4
        for (int i = 0; i < iters; ++i) {
            int t = 4 * i + q;          // t <= 63 always
            // __shfl OUTSIDE any divergent guard: every source lane is active
            // and holds valid (possibly zero-padded) data.
            int s = __shfl(sidx, t);
            float d = __shfl(wv, t);
            float dd = 0.f;
            if (WRITE_Q) dd = __shfl(dv, t);   // compile-time uniform branch
            if (t < cnt) {
                uint4 v = *(const uint4*)(xq + (size_t)s * 128 + ql * 8);
                float f[8];
                unpackq(v, f);
#pragma unroll
                for (int j = 0; j < 8; ++j) acc[j] = fmaf(d, f[j], acc[j]);
                if (WRITE_Q && ql == 0) ssum += dd;
            }
        }
    }

    // butterfly combine: afterwards EVERY lane holds the full sum of its slice
#pragma unroll
    for (int j = 0; j < 8; ++j) {
        acc[j] += __shfl_xor(acc[j], 16);
        acc[j] += __shfl_xor(acc[j], 32);
        acc[j] *= di;
    }

    if (WRITE_Q) {
        ssum += __shfl_xor(ssum, 16);
        ssum += __shfl_xor(ssum, 32);
        if (lane == 0) svec[gw] = di * ssum;
        // row max over the 16 feature slices (all lanes have full slice sums)
        float m = 0.f;
#pragma unroll
        for (int j = 0; j < 8; ++j) m = fmaxf(m, fabsf(acc[j]));
#pragma unroll
        for (int d = 1; d < 16; d <<= 1) m = fmaxf(m, __shfl_xor(m, d));
        float inv = (m > 0.f) ? 32767.f / m : 0.f;
        if (q == 0) {
            uint4 o;
            int q0 = __float2int_rn(acc[0] * inv), q1 = __float2int_rn(acc[1] * inv);
            int q2 = __float2int_rn(acc[2] * inv), q3 = __float2int_rn(acc[3] * inv);
            int q4 = __float2int_rn(acc[4] * inv), q5 = __float2int_rn(acc[5] * inv);
            int q6 = __float2int_rn(acc[6] * inv), q7 = __float2int_rn(acc[7] * inv);
            o.x = ((uint)q0 & 0xFFFFu) | ((uint)q1 << 16);
            o.y = ((uint)q2 & 0xFFFFu) | ((uint)q3 << 16);
            o.z = ((uint)q4 & 0xFFFFu) | ((uint)q5 << 16);
            o.w = ((uint)q6 & 0xFFFFu) | ((uint)q7 << 16);
            *(uint4*)(qout + (size_t)gw * 128 + ql * 8) = o;
        }
        if (lane == 0) mout[gw] = make_float2(di, di * (m * (1.f / 32767.f)));
    } else {
        if (q == 0) {
            float4 o0, o1;
            o0.x = acc[0]; o0.y = acc[1]; o0.z = acc[2]; o0.w = acc[3];
            o1.x = acc[4]; o1.y = acc[5]; o1.z = acc[6]; o1.w = acc[7];
            *(float4*)(fout + (size_t)gw * 128 + ql * 8) = o0;
            *(float4*)(fout + (size_t)gw * 128 + ql * 8 + 4) = o1;
        }
    }
}

// W12 = W1 @ W2  (128x128 @ 128x128), one output per thread.
__global__ void k_w12(const float* __restrict__ W1, const float* __restrict__ W2,
                      float* __restrict__ w12) {
    int idx = blockIdx.x * 256 + threadIdx.x;  // 0..16383
    int i = idx >> 7, j = idx & 127;
    float s = 0.f;
#pragma unroll 8
    for (int k = 0; k < 128; ++k) s = fmaf(W1[i * 128 + k], W2[k * 128 + j], s);
    w12[idx] = s;
}

// cvec = b1^T @ W2  (128,)
__global__ void k_cvec(const float* __restrict__ b1, const float* __restrict__ W2,
                       float* __restrict__ cvec) {
    int j = threadIdx.x;
    float s = 0.f;
#pragma unroll 8
    for (int k = 0; k < 128; ++k) s = fmaf(b1[k], W2[k * 128 + j], s);
    cvec[j] = s;
}

// out = relu( X @ W12 + svec ⊗ cvec + b2 ) — fp32 vector GEMM.
// X tile (64KB) in LDS only; W12 (64KB) read from global: it stays L2-hot
// (re-read ~400MB @ 34TB/s ≈ 12µs chip-wide) and per-16-lane addresses are
// identical (broadcast). LDS 64KB/block -> 2 blocks/CU (4 waves/SIMD): one
// block's staging hides under the other's FMAs (was 1 block/CU, exposed).
// Safe in-place (X == out): block stages its rows into LDS before writing.
__launch_bounds__(512, 4)
__global__ void k_gemm(const float* __restrict__ X, const float* __restrict__ Wg,
                       const float* __restrict__ svec, const float* __restrict__ cvec,
                       const float* __restrict__ b2, float* __restrict__ out, int N) {
    __shared__ float xs[128 * 128];
    int tid = threadIdx.x;
    int row0 = blockIdx.x * 128;

    // stage X rows [row0, row0+128), XOR-swizzled float4 groups
#pragma unroll
    for (int it = 0; it < 8; ++it) {
        int idx = it * 512 + tid;
        int r = idx >> 5, cg = idx & 31;
        int grow = row0 + r;
        float4 v = make_float4(0.f, 0.f, 0.f, 0.f);
        if (grow < N) v = *(const float4*)(X + (size_t)grow * 128 + cg * 4);
        int c0 = (cg * 4) ^ ((r & 7) << 2);
        *(float4*)&xs[r * 128 + c0] = v;
    }
    __syncthreads();

    int ty = tid >> 4, tx = tid & 15;  // 32 x 16 threads
    int r0 = ty * 4;                   // 4 rows per thread
    float acc0[4][4] = {{0.f}};        // cols 4tx..4tx+3
    float acc1[4][4] = {{0.f}};        // cols 64+4tx..+3

#pragma unroll 2
    for (int k0 = 0; k0 < 128; k0 += 4) {
        float4 w0[4], w1[4];
#pragma unroll
        for (int kk = 0; kk < 4; ++kk) {
            w0[kk] = *(const float4*)&Wg[(k0 + kk) * 128 + 4 * tx];
            w1[kk] = *(const float4*)&Wg[(k0 + kk) * 128 + 64 + 4 * tx];
        }
#pragma unroll
        for (int j = 0; j < 4; ++j) {
            int r = r0 + j;
            float4 a = *(const float4*)&xs[r * 128 + (k0 ^ ((r & 7) << 2))];
            float av[4] = {a.x, a.y, a.z, a.w};
#pragma unroll
            for (int kk = 0; kk < 4; ++kk) {
                acc0[j][0] = fmaf(av[kk], w0[kk].x, acc0[j][0]);
                acc0[j][1] = fmaf(av[kk], w0[kk].y, acc0[j][1]);
                acc0[j][2] = fmaf(av[kk], w0[kk].z, acc0[j][2]);
                acc0[j][3] = fmaf(av[kk], w0[kk].w, acc0[j][3]);
                acc1[j][0] = fmaf(av[kk], w1[kk].x, acc1[j][0]);
                acc1[j][1] = fmaf(av[kk], w1[kk].y, acc1[j][1]);
                acc1[j][2] = fmaf(av[kk], w1[kk].z, acc1[j][2]);
                acc1[j][3] = fmaf(av[kk], w1[kk].w, acc1[j][3]);
            }
        }
    }

    float c0v[4], c1v[4], b0v[4], b1v[4];
#pragma unroll
    for (int m = 0; m < 4; ++m) {
        c0v[m] = cvec[4 * tx + m];
        c1v[m] = cvec[64 + 4 * tx + m];
        b0v[m] = b2[4 * tx + m];
        b1v[m] = b2[64 + 4 * tx + m];
    }
#pragma unroll
    for (int j = 0; j < 4; ++j) {
        int grow = row0 + r0 + j;
        if (grow >= N) continue;
        float sv = svec[grow];
        float4 o0, o1;
        o0.x = fmaxf(acc0[j][0] + sv * c0v[0] + b0v[0], 0.f);
        o0.y = fmaxf(acc0[j][1] + sv * c0v[1] + b0v[1], 0.f);
        o0.z = fmaxf(acc0[j][2] + sv * c0v[2] + b0v[2], 0.f);
        o0.w = fmaxf(acc0[j][3] + sv * c0v[3] + b0v[3], 0.f);
        o1.x = fmaxf(acc1[j][0] + sv * c1v[0] + b1v[0], 0.f);
        o1.y = fmaxf(acc1[j][1] + sv * c1v[1] + b1v[1], 0.f);
        o1.z = fmaxf(acc1[j][2] + sv * c1v[2] + b1v[2], 0.f);
        o1.w = fmaxf(acc1[j][3] + sv * c1v[3] + b1v[3], 0.f);
        *(float4*)&out[(size_t)grow * 128 + 4 * tx] = o0;
        *(float4*)&out[(size_t)grow * 128 + 64 + 4 * tx] = o1;
    }
}

extern "C" void kernel_launch(void* const* d_in, const int* in_sizes, int n_in,
                              void* d_out, int out_size, void* d_ws, size_t ws_size,
                              hipStream_t stream) {
    const float* x  = (const float*)d_in[0];
    const int*   ei = (const int*)d_in[1];
    const float* W1 = (const float*)d_in[2];
    const float* b1 = (const float*)d_in[3];
    const float* W2 = (const float*)d_in[4];
    const float* b2 = (const float*)d_in[5];
    float* out = (float*)d_out;

    int N = in_sizes[0] / 128;
    int E = in_sizes[1] / 2;
    const int* srcE = ei;
    const int* dstE = ei + E;

    char* w = (char*)d_ws;
    size_t off = 0;
    auto alloc = [&](size_t bytes) {
        void* p = w + off;
        off = WS_ALIGN(off + bytes);
        return p;
    };
    ushort* xq    = (ushort*)alloc((size_t)N * 256);
    ushort* t1q   = (ushort*)alloc((size_t)N * 256);   // rank aliases here early
    int*   csr    = (int*)alloc((size_t)E * 4);
    float2* meta1 = (float2*)alloc((size_t)N * 8);
    float2* meta2 = (float2*)alloc((size_t)N * 8);
    int*   deg    = (int*)alloc((size_t)N * 4);
    int*   offs   = (int*)alloc((size_t)(N + 1) * 4);
    int*   bsums  = (int*)alloc(4096);
    float* dinv   = (float*)alloc((size_t)N * 4);
    float* svec   = (float*)alloc((size_t)N * 4);
    float* w12    = (float*)alloc(128 * 128 * 4);
    float* cvec   = (float*)alloc(128 * 4);
    (void)ws_size; (void)n_in; (void)out_size;

    int nb = (N + 255) / 256;  // 391 for N=100000, fits k_scan2's 512
    int eb8 = (E + 8 * 256 - 1) / (8 * 256);
    int* rank = (int*)t1q;  // dead before t1q is written (stream-ordered)

    k_init_deg<<<(N + 255) / 256, 256, 0, stream>>>(deg, N);
    k_rank<<<eb8, 256, 0, stream>>>(dstE, deg, rank, E, N);
    k_dinv<<<(N + 255) / 256, 256, 0, stream>>>(deg, dinv, N);
    k_scan1<<<nb, 256, 0, stream>>>(deg, offs, bsums, N);
    k_scan2<<<1, 512, 0, stream>>>(bsums, nb);
    k_scan3<<<nb, 256, 0, stream>>>(offs, bsums, N, E);
    k_fill<<<eb8, 256, 0, stream>>>(srcE, dstE, rank, offs, csr, E, N);
    // quantize x (rank is dead from here; t1q may overwrite it)
    k_toq16<<<(N + 3) / 4, 256, 0, stream>>>(x, dinv, xq, meta1, N);
    // pass 1: t1 = A x   (int16 in, int16 out) + svec = rowsum(A)
    k_aggq<1><<<(N + 3) / 4, 256, 0, stream>>>(xq, meta1, nullptr, t1q, meta2, svec,
                                               offs, csr, N);
    // pass 2: t2 = A t1  (int16 in, f32 out -> d_out as scratch)
    k_aggq<0><<<(N + 3) / 4, 256, 0, stream>>>(t1q, meta2, out, nullptr, nullptr, nullptr,
                                               offs, csr, N);
    k_w12<<<64, 256, 0, stream>>>(W1, W2, w12);
    k_cvec<<<1, 128, 0, stream>>>(b1, W2, cvec);
    // out = relu(t2 @ W12 + svec ⊗ cvec + b2), in-place on d_out
    k_gemm<<<(N + 127) / 128, 512, 0, stream>>>(out, w12, svec, cvec, b2, out, N);
}

// Round 9
// 313.998 us; speedup vs baseline: 1.3107x; 1.1429x over previous
//
#include <hip/hip_runtime.h>

// GCN 2-layer fused:  out = relu( A·(A·x)·(W1@W2) + (A·1)⊗(b1ᵀW2) + b2 )
// A = D^-1/2 (Adj + I) D^-1/2.  Both aggregation passes gather int16 rows
// with per-row dynamic scale. Pass 2 writes f32 t2 into d_out; the final
// GEMM runs on MFMA (bf16 split-precision: X@W = Xhi·Whi + Xlo·Whi + Xhi·Wlo,
// rel err ~2^-17) in-place on d_out.

#define WS_ALIGN(x) (((x) + 255) & ~(size_t)255)

typedef __attribute__((ext_vector_type(8))) short bf16x8;
typedef __attribute__((ext_vector_type(4))) float f32x4;

__device__ inline ushort bf16rn(float f) {
    uint u = __float_as_uint(f);
    u = (u + 0x7FFFu + ((u >> 16) & 1u)) >> 16;
    return (ushort)u;
}
__device__ inline float bf16tof(ushort h) {
    return __uint_as_float(((uint)h) << 16);
}

__global__ void k_init_deg(int* __restrict__ deg, int N) {
    int i = blockIdx.x * blockDim.x + threadIdx.x;
    if (i < N) deg[i] = 0;   // real edges only; self-loop added in dinv
}

// degree count + within-segment rank (atomicAdd return). rank write coalesced.
__global__ void k_rank(const int* __restrict__ dst, int* __restrict__ deg,
                       int* __restrict__ rank, int E, int N) {
    int tid = blockIdx.x * blockDim.x + threadIdx.x;
    int stride = gridDim.x * blockDim.x;
#pragma unroll
    for (int it = 0; it < 8; ++it) {
        int e = tid + it * stride;
        if (e < E) {
            int d = dst[e];
            if ((unsigned)d < (unsigned)N) rank[e] = atomicAdd(&deg[d], 1);
        }
    }
}

__global__ void k_dinv(const int* __restrict__ deg, float* __restrict__ dinv, int N) {
    int i = blockIdx.x * blockDim.x + threadIdx.x;
    if (i < N) dinv[i] = rsqrtf((float)(deg[i] + 1));
}

// Block-local exclusive scan of deg (256/block), emits block sums.
__global__ void k_scan1(const int* __restrict__ deg, int* __restrict__ offs,
                        int* __restrict__ bsums, int N) {
    __shared__ int sh[256];
    int i = blockIdx.x * 256 + threadIdx.x;
    int v = (i < N) ? deg[i] : 0;
    sh[threadIdx.x] = v;
    __syncthreads();
    for (int off = 1; off < 256; off <<= 1) {
        int t = (threadIdx.x >= off) ? sh[threadIdx.x - off] : 0;
        __syncthreads();
        sh[threadIdx.x] += t;
        __syncthreads();
    }
    if (i < N) offs[i] = sh[threadIdx.x] - v;
    if (threadIdx.x == 255) bsums[blockIdx.x] = sh[255];
}

// Exclusive scan of up to 512 block sums in one block.
__global__ void k_scan2(int* __restrict__ bsums, int nb) {
    __shared__ int sh[512];
    int tid = threadIdx.x;
    int v = (tid < nb) ? bsums[tid] : 0;
    sh[tid] = v;
    __syncthreads();
    for (int off = 1; off < 512; off <<= 1) {
        int t = (tid >= off) ? sh[tid - off] : 0;
        __syncthreads();
        sh[tid] += t;
        __syncthreads();
    }
    if (tid < nb) bsums[tid] = sh[tid] - v;
}

__global__ void k_scan3(int* __restrict__ offs, const int* __restrict__ bsums, int N, int E) {
    int i = blockIdx.x * 256 + threadIdx.x;
    if (i < N) offs[i] += bsums[blockIdx.x];
    if (blockIdx.x == 0 && threadIdx.x == 0) offs[N] = E;
}

// Atomic-free CSR fill: slot = offs[dst] + rank. Fire-and-forget scatter.
__global__ void k_fill(const int* __restrict__ src, const int* __restrict__ dst,
                       const int* __restrict__ rank, const int* __restrict__ offs,
                       int* __restrict__ csr, int E, int N) {
    int tid = blockIdx.x * blockDim.x + threadIdx.x;
    int stride = gridDim.x * blockDim.x;
#pragma unroll
    for (int it = 0; it < 8; ++it) {
        int e = tid + it * stride;
        if (e < E) {
            int d = dst[e];
            int s = src[e];
            int r = rank[e];
            if ((unsigned)d < (unsigned)N && (unsigned)s < (unsigned)N)
                csr[offs[d] + r] = s;
        }
    }
}

// x (f32) -> int16 with per-row scale. One wave per row; lane owns 2 elems.
// meta[i] = (dinv[i], dinv[i]*scale[i]) -> the fused gather weight.
__launch_bounds__(256)
__global__ void k_toq16(const float* __restrict__ x, const float* __restrict__ dinv,
                        ushort* __restrict__ xq, float2* __restrict__ meta, int N) {
    int gw = (int)((blockIdx.x * (size_t)blockDim.x + threadIdx.x) >> 6);
    int lane = threadIdx.x & 63;
    if (gw >= N) return;
    float2 v = ((const float2*)(x + (size_t)gw * 128))[lane];
    float m = fmaxf(fabsf(v.x), fabsf(v.y));
#pragma unroll
    for (int d = 1; d < 64; d <<= 1) m = fmaxf(m, __shfl_xor(m, d));
    float inv = (m > 0.f) ? 32767.f / m : 0.f;
    int qa = __float2int_rn(v.x * inv);
    int qb = __float2int_rn(v.y * inv);
    uint packed = ((uint)qa & 0xFFFFu) | ((uint)qb << 16);
    ((uint*)xq)[(size_t)gw * 64 + lane] = packed;
    if (lane == 0) {
        float di = dinv[gw];
        meta[gw] = make_float2(di, di * (m * (1.f / 32767.f)));
    }
}

__device__ inline void unpackq(uint4 v, float f[8]) {
    f[0] = (float)(short)(v.x & 0xFFFFu);
    f[1] = (float)((int)v.x >> 16);
    f[2] = (float)(short)(v.y & 0xFFFFu);
    f[3] = (float)((int)v.y >> 16);
    f[4] = (float)(short)(v.z & 0xFFFFu);
    f[5] = (float)((int)v.z >> 16);
    f[6] = (float)(short)(v.w & 0xFFFFu);
    f[7] = (float)((int)v.w >> 16);
}

// Aggregation over int16 rows (round-6 proven structure). One wave per node;
// quarter-wave (16 lanes) covers a 256B int16 row via uint4 -> 4 neighbor
// rows in flight/iteration. csr/meta loaded once per 64-edge chunk;
// all __shfl executed unconditionally (exec-masked bpermute is undefined).
template <int WRITE_Q>
__launch_bounds__(256)
__global__ void k_aggq(const ushort* __restrict__ xq, const float2* __restrict__ meta,
                       float* __restrict__ fout,
                       ushort* __restrict__ qout, float2* __restrict__ mout,
                       float* __restrict__ svec,
                       const int* __restrict__ offs, const int* __restrict__ csr, int N) {
    int gw = (int)((blockIdx.x * (size_t)blockDim.x + threadIdx.x) >> 6);
    int lane = threadIdx.x & 63;
    if (gw >= N) return;
    int q = lane >> 4, ql = lane & 15;
    float2 ms = meta[gw];
    float di = ms.x;

    float acc[8];
#pragma unroll
    for (int j = 0; j < 8; ++j) acc[j] = 0.f;
    float ssum = (lane == 0) ? di : 0.f;

    if (q == 0) {  // self term: weight di*scale_self = ms.y
        uint4 v = *(const uint4*)(xq + (size_t)gw * 128 + ql * 8);
        float f[8];
        unpackq(v, f);
#pragma unroll
        for (int j = 0; j < 8; ++j) acc[j] = ms.y * f[j];
    }

    int s0 = offs[gw], s1 = offs[gw + 1];
    for (int base = s0; base < s1; base += 64) {
        int cnt = min(64, s1 - base);
        int sidx = 0;
        float wv = 0.f, dv = 0.f;   // lanes >= cnt keep 0 -> d==0 for padded t
        if (lane < cnt) {
            sidx = csr[base + lane];
            float2 mm = meta[sidx];
            dv = mm.x;
            wv = mm.y;
        }
        int iters = (cnt + 3) >> 2;
#pragma unroll 4
        for (int i = 0; i < iters; ++i) {
            int t = 4 * i + q;          // t <= 63 always
            int s = __shfl(sidx, t);
            float d = __shfl(wv, t);
            float dd = 0.f;
            if (WRITE_Q) dd = __shfl(dv, t);   // compile-time uniform branch
            if (t < cnt) {
                uint4 v = *(const uint4*)(xq + (size_t)s * 128 + ql * 8);
                float f[8];
                unpackq(v, f);
#pragma unroll
                for (int j = 0; j < 8; ++j) acc[j] = fmaf(d, f[j], acc[j]);
                if (WRITE_Q && ql == 0) ssum += dd;
            }
        }
    }

    // butterfly combine: afterwards EVERY lane holds the full sum of its slice
#pragma unroll
    for (int j = 0; j < 8; ++j) {
        acc[j] += __shfl_xor(acc[j], 16);
        acc[j] += __shfl_xor(acc[j], 32);
        acc[j] *= di;
    }

    if (WRITE_Q) {
        ssum += __shfl_xor(ssum, 16);
        ssum += __shfl_xor(ssum, 32);
        if (lane == 0) svec[gw] = di * ssum;
        float m = 0.f;
#pragma unroll
        for (int j = 0; j < 8; ++j) m = fmaxf(m, fabsf(acc[j]));
#pragma unroll
        for (int d = 1; d < 16; d <<= 1) m = fmaxf(m, __shfl_xor(m, d));
        float inv = (m > 0.f) ? 32767.f / m : 0.f;
        if (q == 0) {
            uint4 o;
            int q0 = __float2int_rn(acc[0] * inv), q1 = __float2int_rn(acc[1] * inv);
            int q2 = __float2int_rn(acc[2] * inv), q3 = __float2int_rn(acc[3] * inv);
            int q4 = __float2int_rn(acc[4] * inv), q5 = __float2int_rn(acc[5] * inv);
            int q6 = __float2int_rn(acc[6] * inv), q7 = __float2int_rn(acc[7] * inv);
            o.x = ((uint)q0 & 0xFFFFu) | ((uint)q1 << 16);
            o.y = ((uint)q2 & 0xFFFFu) | ((uint)q3 << 16);
            o.z = ((uint)q4 & 0xFFFFu) | ((uint)q5 << 16);
            o.w = ((uint)q6 & 0xFFFFu) | ((uint)q7 << 16);
            *(uint4*)(qout + (size_t)gw * 128 + ql * 8) = o;
        }
        if (lane == 0) mout[gw] = make_float2(di, di * (m * (1.f / 32767.f)));
    } else {
        if (q == 0) {
            float4 o0, o1;
            o0.x = acc[0]; o0.y = acc[1]; o0.z = acc[2]; o0.w = acc[3];
            o1.x = acc[4]; o1.y = acc[5]; o1.z = acc[6]; o1.w = acc[7];
            *(float4*)(fout + (size_t)gw * 128 + ql * 8) = o0;
            *(float4*)(fout + (size_t)gw * 128 + ql * 8 + 4) = o1;
        }
    }
}

// W12 = W1 @ W2  (128x128 @ 128x128) f32, one output per thread.
__global__ void k_w12(const float* __restrict__ W1, const float* __restrict__ W2,
                      float* __restrict__ w12) {
    int idx = blockIdx.x * 256 + threadIdx.x;  // 0..16383
    int i = idx >> 7, j = idx & 127;
    float s = 0.f;
#pragma unroll 8
    for (int k = 0; k < 128; ++k) s = fmaf(W1[i * 128 + k], W2[k * 128 + j], s);
    w12[idx] = s;
}

// Pack W12 into MFMA B-fragment order, bf16 hi + lo residual.
// Fragment (nt, kb): lane l holds B[kb*32 + (l>>4)*8 + i][nt*16 + (l&15)],
// i = 0..7, stored as 16B at ((nt*4+kb)*64 + l)*16.
__global__ void k_wpack(const float* __restrict__ w12,
                        ushort* __restrict__ wph, ushort* __restrict__ wpl) {
    int idx = blockIdx.x * 256 + threadIdx.x;  // 0..2047
    int lane = idx & 63;
    int kb = (idx >> 6) & 3;
    int nt = idx >> 8;
    int n = nt * 16 + (lane & 15);
    int k0 = kb * 32 + (lane >> 4) * 8;
    ushort h[8], l[8];
#pragma unroll
    for (int i = 0; i < 8; ++i) {
        float f = w12[(k0 + i) * 128 + n];
        h[i] = bf16rn(f);
        l[i] = bf16rn(f - bf16tof(h[i]));
    }
    uint4 oh, ol;
    oh.x = (uint)h[0] | ((uint)h[1] << 16);
    oh.y = (uint)h[2] | ((uint)h[3] << 16);
    oh.z = (uint)h[4] | ((uint)h[5] << 16);
    oh.w = (uint)h[6] | ((uint)h[7] << 16);
    ol.x = (uint)l[0] | ((uint)l[1] << 16);
    ol.y = (uint)l[2] | ((uint)l[3] << 16);
    ol.z = (uint)l[4] | ((uint)l[5] << 16);
    ol.w = (uint)l[6] | ((uint)l[7] << 16);
    ((uint4*)wph)[idx] = oh;
    ((uint4*)wpl)[idx] = ol;
}

// cvec = b1^T @ W2  (128,)
__global__ void k_cvec(const float* __restrict__ b1, const float* __restrict__ W2,
                       float* __restrict__ cvec) {
    int j = threadIdx.x;
    float s = 0.f;
#pragma unroll 8
    for (int k = 0; k < 128; ++k) s = fmaf(b1[k], W2[k * 128 + j], s);
    cvec[j] = s;
}

// out = relu( X @ W12 + svec ⊗ cvec + b2 ) — MFMA bf16 split-precision.
// 256 threads / 4 waves; block covers 128 rows; wave owns 32 rows (2 strips
// of 16) x all 8 col-tiles. X read as f32, hi/lo bf16 built in-register.
// W fragments (hi+lo, 64KB) staged in LDS -> 2 blocks/CU.
// In-place safe (X == out): all A loads precede all stores within a block.
__launch_bounds__(256)
__global__ void k_gemm_mfma(const float* __restrict__ X,
                            const ushort* __restrict__ wph, const ushort* __restrict__ wpl,
                            const float* __restrict__ svec, const float* __restrict__ cvec,
                            const float* __restrict__ b2, float* __restrict__ out, int N) {
    __shared__ uint4 wsh[2048];  // 32 KB
    __shared__ uint4 wsl[2048];  // 32 KB
    int tid = threadIdx.x;
    int lane = tid & 63;
    int wv = tid >> 6;
    int row0 = blockIdx.x * 128;

    // stage packed W fragments
#pragma unroll
    for (int it = 0; it < 8; ++it) {
        wsh[it * 256 + tid] = ((const uint4*)wph)[it * 256 + tid];
        wsl[it * 256 + tid] = ((const uint4*)wpl)[it * 256 + tid];
    }

    // A fragments: strip s (16 rows), k-block kb (32 cols of K).
    // lane l: row = base + (l&15), k = kb*32 + (l>>4)*8 + i
    bf16x8 ah[2][4], al[2][4];
#pragma unroll
    for (int s = 0; s < 2; ++s) {
#pragma unroll
        for (int kb = 0; kb < 4; ++kb) {
            int row = row0 + wv * 32 + s * 16 + (lane & 15);
            int kbase = kb * 32 + (lane >> 4) * 8;
            float f[8];
            if (row < N) {
                float4 a = *(const float4*)(X + (size_t)row * 128 + kbase);
                float4 b = *(const float4*)(X + (size_t)row * 128 + kbase + 4);
                f[0] = a.x; f[1] = a.y; f[2] = a.z; f[3] = a.w;
                f[4] = b.x; f[5] = b.y; f[6] = b.z; f[7] = b.w;
            } else {
#pragma unroll
                for (int i = 0; i < 8; ++i) f[i] = 0.f;
            }
            bf16x8 hh, ll;
#pragma unroll
            for (int i = 0; i < 8; ++i) {
                ushort h = bf16rn(f[i]);
                hh[i] = (short)h;
                ll[i] = (short)bf16rn(f[i] - bf16tof(h));
            }
            ah[s][kb] = hh;
            al[s][kb] = ll;
        }
    }
    __syncthreads();

    f32x4 acc[2][8];
#pragma unroll
    for (int s = 0; s < 2; ++s)
#pragma unroll
        for (int nt = 0; nt < 8; ++nt) acc[s][nt] = (f32x4)(0.f);

#pragma unroll
    for (int nt = 0; nt < 8; ++nt) {
#pragma unroll
        for (int kb = 0; kb < 4; ++kb) {
            uint4 rh = wsh[(nt * 4 + kb) * 64 + lane];
            uint4 rl = wsl[(nt * 4 + kb) * 64 + lane];
            bf16x8 bh = __builtin_bit_cast(bf16x8, rh);
            bf16x8 bl = __builtin_bit_cast(bf16x8, rl);
            acc[0][nt] = __builtin_amdgcn_mfma_f32_16x16x32_bf16(ah[0][kb], bh, acc[0][nt], 0, 0, 0);
            acc[0][nt] = __builtin_amdgcn_mfma_f32_16x16x32_bf16(al[0][kb], bh, acc[0][nt], 0, 0, 0);
            acc[0][nt] = __builtin_amdgcn_mfma_f32_16x16x32_bf16(ah[0][kb], bl, acc[0][nt], 0, 0, 0);
            acc[1][nt] = __builtin_amdgcn_mfma_f32_16x16x32_bf16(ah[1][kb], bh, acc[1][nt], 0, 0, 0);
            acc[1][nt] = __builtin_amdgcn_mfma_f32_16x16x32_bf16(al[1][kb], bh, acc[1][nt], 0, 0, 0);
            acc[1][nt] = __builtin_amdgcn_mfma_f32_16x16x32_bf16(ah[1][kb], bl, acc[1][nt], 0, 0, 0);
        }
    }

    // epilogue: D elem r -> row_local = (lane>>4)*4 + r, col = nt*16 + (lane&15)
    float cv[8], bv[8];
#pragma unroll
    for (int nt = 0; nt < 8; ++nt) {
        cv[nt] = cvec[nt * 16 + (lane & 15)];
        bv[nt] = b2[nt * 16 + (lane & 15)];
    }
#pragma unroll
    for (int s = 0; s < 2; ++s) {
#pragma unroll
        for (int r = 0; r < 4; ++r) {
            int row = row0 + wv * 32 + s * 16 + (lane >> 4) * 4 + r;
            if (row < N) {
                float sv = svec[row];
#pragma unroll
                for (int nt = 0; nt < 8; ++nt) {
                    float o = fmaxf(acc[s][nt][r] + sv * cv[nt] + bv[nt], 0.f);
                    out[(size_t)row * 128 + nt * 16 + (lane & 15)] = o;
                }
            }
        }
    }
}

extern "C" void kernel_launch(void* const* d_in, const int* in_sizes, int n_in,
                              void* d_out, int out_size, void* d_ws, size_t ws_size,
                              hipStream_t stream) {
    const float* x  = (const float*)d_in[0];
    const int*   ei = (const int*)d_in[1];
    const float* W1 = (const float*)d_in[2];
    const float* b1 = (const float*)d_in[3];
    const float* W2 = (const float*)d_in[4];
    const float* b2 = (const float*)d_in[5];
    float* out = (float*)d_out;

    int N = in_sizes[0] / 128;
    int E = in_sizes[1] / 2;
    const int* srcE = ei;
    const int* dstE = ei + E;

    char* w = (char*)d_ws;
    size_t off = 0;
    auto alloc = [&](size_t bytes) {
        void* p = w + off;
        off = WS_ALIGN(off + bytes);
        return p;
    };
    ushort* xq    = (ushort*)alloc((size_t)N * 256);
    ushort* t1q   = (ushort*)alloc((size_t)N * 256);   // rank aliases here early
    int*   csr    = (int*)alloc((size_t)E * 4);
    float2* meta1 = (float2*)alloc((size_t)N * 8);
    float2* meta2 = (float2*)alloc((size_t)N * 8);
    int*   deg    = (int*)alloc((size_t)N * 4);
    int*   offs   = (int*)alloc((size_t)(N + 1) * 4);
    int*   bsums  = (int*)alloc(4096);
    float* dinv   = (float*)alloc((size_t)N * 4);
    float* svec   = (float*)alloc((size_t)N * 4);
    float* w12    = (float*)alloc(128 * 128 * 4);
    ushort* wph   = (ushort*)alloc(128 * 128 * 2);
    ushort* wpl   = (ushort*)alloc(128 * 128 * 2);
    float* cvec   = (float*)alloc(128 * 4);
    (void)ws_size; (void)n_in; (void)out_size;

    int nb = (N + 255) / 256;  // 391 for N=100000, fits k_scan2's 512
    int eb8 = (E + 8 * 256 - 1) / (8 * 256);
    int* rank = (int*)t1q;  // dead before t1q is written (stream-ordered)

    k_init_deg<<<(N + 255) / 256, 256, 0, stream>>>(deg, N);
    k_rank<<<eb8, 256, 0, stream>>>(dstE, deg, rank, E, N);
    k_dinv<<<(N + 255) / 256, 256, 0, stream>>>(deg, dinv, N);
    k_scan1<<<nb, 256, 0, stream>>>(deg, offs, bsums, N);
    k_scan2<<<1, 512, 0, stream>>>(bsums, nb);
    k_scan3<<<nb, 256, 0, stream>>>(offs, bsums, N, E);
    k_fill<<<eb8, 256, 0, stream>>>(srcE, dstE, rank, offs, csr, E, N);
    // quantize x (rank is dead from here; t1q may overwrite it)
    k_toq16<<<(N + 3) / 4, 256, 0, stream>>>(x, dinv, xq, meta1, N);
    // pass 1: t1 = A x   (int16 in, int16 out) + svec = rowsum(A)
    k_aggq<1><<<(N + 3) / 4, 256, 0, stream>>>(xq, meta1, nullptr, t1q, meta2, svec,
                                               offs, csr, N);
    // pass 2: t2 = A t1  (int16 in, f32 out -> d_out as scratch)
    k_aggq<0><<<(N + 3) / 4, 256, 0, stream>>>(t1q, meta2, out, nullptr, nullptr, nullptr,
                                               offs, csr, N);
    k_w12<<<64, 256, 0, stream>>>(W1, W2, w12);
    k_wpack<<<8, 256, 0, stream>>>(w12, wph, wpl);
    k_cvec<<<1, 128, 0, stream>>>(b1, W2, cvec);
    // out = relu(t2 @ W12 + svec ⊗ cvec + b2), MFMA, in-place on d_out
    k_gemm_mfma<<<(N + 127) / 128, 256, 0, stream>>>(out, wph, wpl, svec, cvec, b2, out, N);
}

// Round 10
// 296.996 us; speedup vs baseline: 1.3857x; 1.0572x over previous
//
#include <hip/hip_runtime.h>

// GCN 2-layer fused:  out = relu( A·(A·x)·(W1@W2) + (A·1)⊗(b1ᵀW2) + b2 )
// A = D^-1/2 (Adj + I) D^-1/2.  Both aggregation passes gather f16 rows
// (no row scaling needed — f16 exponent handles range; inner loop compiles
// to v_fma_mix_f32). Pass 2 writes f32 t2 into d_out; final GEMM is MFMA
// bf16 split-precision (X@W = Xhi·Whi + Xlo·Whi + Xhi·Wlo), in-place.
// All __shfl executed unconditionally (exec-masked ds_bpermute undefined).

#define WS_ALIGN(x) (((x) + 255) & ~(size_t)255)

typedef __attribute__((ext_vector_type(8))) short bf16x8;
typedef __attribute__((ext_vector_type(4))) float f32x4;
typedef _Float16 f16x8 __attribute__((ext_vector_type(8)));
typedef _Float16 f16x4 __attribute__((ext_vector_type(4)));

__device__ inline ushort bf16rn(float f) {
    uint u = __float_as_uint(f);
    u = (u + 0x7FFFu + ((u >> 16) & 1u)) >> 16;
    return (ushort)u;
}
__device__ inline float bf16tof(ushort h) {
    return __uint_as_float(((uint)h) << 16);
}

// degree count + within-segment rank (atomicAdd return). rank write coalesced.
__global__ void k_rank(const int* __restrict__ dst, int* __restrict__ deg,
                       int* __restrict__ rank, int E, int N) {
    int tid = blockIdx.x * blockDim.x + threadIdx.x;
    int stride = gridDim.x * blockDim.x;
#pragma unroll
    for (int it = 0; it < 8; ++it) {
        int e = tid + it * stride;
        if (e < E) {
            int d = dst[e];
            if ((unsigned)d < (unsigned)N) rank[e] = atomicAdd(&deg[d], 1);
        }
    }
}

// Block-local exclusive scan of deg (256/block), emits block sums. Also
// computes dinv = rsqrt(deg+1) (self-loop) — fused to save a pass.
__global__ void k_scan1(const int* __restrict__ deg, int* __restrict__ offs,
                        int* __restrict__ bsums, float* __restrict__ dinv, int N) {
    __shared__ int sh[256];
    int i = blockIdx.x * 256 + threadIdx.x;
    int v = (i < N) ? deg[i] : 0;
    if (i < N) dinv[i] = rsqrtf((float)(v + 1));
    sh[threadIdx.x] = v;
    __syncthreads();
    for (int off = 1; off < 256; off <<= 1) {
        int t = (threadIdx.x >= off) ? sh[threadIdx.x - off] : 0;
        __syncthreads();
        sh[threadIdx.x] += t;
        __syncthreads();
    }
    if (i < N) offs[i] = sh[threadIdx.x] - v;
    if (threadIdx.x == 255) bsums[blockIdx.x] = sh[255];
}

// Exclusive scan of up to 512 block sums in one block.
__global__ void k_scan2(int* __restrict__ bsums, int nb) {
    __shared__ int sh[512];
    int tid = threadIdx.x;
    int v = (tid < nb) ? bsums[tid] : 0;
    sh[tid] = v;
    __syncthreads();
    for (int off = 1; off < 512; off <<= 1) {
        int t = (tid >= off) ? sh[tid - off] : 0;
        __syncthreads();
        sh[tid] += t;
        __syncthreads();
    }
    if (tid < nb) bsums[tid] = sh[tid] - v;
}

__global__ void k_scan3(int* __restrict__ offs, const int* __restrict__ bsums, int N, int E) {
    int i = blockIdx.x * 256 + threadIdx.x;
    if (i < N) offs[i] += bsums[blockIdx.x];
    if (blockIdx.x == 0 && threadIdx.x == 0) offs[N] = E;
}

// Atomic-free CSR fill: slot = offs[dst] + rank. Fire-and-forget scatter.
__global__ void k_fill(const int* __restrict__ src, const int* __restrict__ dst,
                       const int* __restrict__ rank, const int* __restrict__ offs,
                       int* __restrict__ csr, int E, int N) {
    int tid = blockIdx.x * blockDim.x + threadIdx.x;
    int stride = gridDim.x * blockDim.x;
#pragma unroll
    for (int it = 0; it < 8; ++it) {
        int e = tid + it * stride;
        if (e < E) {
            int d = dst[e];
            int s = src[e];
            int r = rank[e];
            if ((unsigned)d < (unsigned)N && (unsigned)s < (unsigned)N)
                csr[offs[d] + r] = s;
        }
    }
}

// x (f32) -> f16, plain convert (no scaling), 4 elems/thread.
__global__ void k_tof16(const float* __restrict__ x, ushort* __restrict__ xh, int n4) {
    int i = blockIdx.x * blockDim.x + threadIdx.x;
    int stride = gridDim.x * blockDim.x;
    for (; i < n4; i += stride) {
        float4 v = ((const float4*)x)[i];
        f16x4 h;
        h[0] = (_Float16)v.x;
        h[1] = (_Float16)v.y;
        h[2] = (_Float16)v.z;
        h[3] = (_Float16)v.w;
        ((uint2*)xh)[i] = __builtin_bit_cast(uint2, h);
    }
}

// Aggregation over f16 rows (round-6 proven gather structure). One wave per
// node; quarter-wave (16 lanes) covers a 256B f16 row via uint4 -> 4 neighbor
// rows in flight/iteration. csr/dinv loaded once per 64-edge chunk; edge
// params distributed via bpermute (always exec'd by all lanes). Inner math:
// fmaf(d, (float)f16, acc) -> v_fma_mix_f32 (1 instr/elem, no unpack chain).
// WRITE_Q=1: output f16 rows (plain convert) + svec = rowsum(A).
// WRITE_Q=0: output f32 rows to fout.
template <int WRITE_Q>
__launch_bounds__(256)
__global__ void k_aggq(const ushort* __restrict__ xh, const float* __restrict__ dinv,
                       float* __restrict__ fout, ushort* __restrict__ qout,
                       float* __restrict__ svec,
                       const int* __restrict__ offs, const int* __restrict__ csr, int N) {
    int gw = (int)((blockIdx.x * (size_t)blockDim.x + threadIdx.x) >> 6);
    int lane = threadIdx.x & 63;
    if (gw >= N) return;
    int q = lane >> 4, ql = lane & 15;
    float di = dinv[gw];
    const uint4* __restrict__ xh4 = (const uint4*)xh;

    float acc[8];
#pragma unroll
    for (int j = 0; j < 8; ++j) acc[j] = 0.f;
    float ssum = (lane == 0) ? di : 0.f;

    if (q == 0) {  // self term
        uint4 v = xh4[((size_t)gw << 4) + ql];
        f16x8 h = __builtin_bit_cast(f16x8, v);
#pragma unroll
        for (int j = 0; j < 8; ++j) acc[j] = di * (float)h[j];
    }

    int s0 = offs[gw], s1 = offs[gw + 1];
    for (int base = s0; base < s1; base += 64) {
        int cnt = min(64, s1 - base);
        int sidx = 0;
        float dv = 0.f;   // lanes >= cnt keep 0 -> padded t contributes 0
        if (lane < cnt) {
            sidx = csr[base + lane];
            dv = dinv[sidx];
        }
        int iters = (cnt + 3) >> 2;
#pragma unroll 4
        for (int i = 0; i < iters; ++i) {
            int t = 4 * i + q;          // t <= 63 always
            // __shfl OUTSIDE the divergent guard (all source lanes active)
            int s = __shfl(sidx, t);
            float d = __shfl(dv, t);
            if (t < cnt) {
                uint4 v = xh4[((size_t)s << 4) + ql];
                f16x8 h = __builtin_bit_cast(f16x8, v);
#pragma unroll
                for (int j = 0; j < 8; ++j) acc[j] = fmaf(d, (float)h[j], acc[j]);
                if (WRITE_Q && ql == 0) ssum += d;
            }
        }
    }

    // butterfly combine: afterwards EVERY lane holds the full sum of its slice
#pragma unroll
    for (int j = 0; j < 8; ++j) {
        acc[j] += __shfl_xor(acc[j], 16);
        acc[j] += __shfl_xor(acc[j], 32);
        acc[j] *= di;
    }

    if (WRITE_Q) {
        ssum += __shfl_xor(ssum, 16);
        ssum += __shfl_xor(ssum, 32);
        if (lane == 0) svec[gw] = di * ssum;
        if (q == 0) {   // plain f32 -> f16 convert, no row max needed
            f16x8 hh;
#pragma unroll
            for (int j = 0; j < 8; ++j) hh[j] = (_Float16)acc[j];
            *(uint4*)(qout + (size_t)gw * 128 + ql * 8) = __builtin_bit_cast(uint4, hh);
        }
    } else {
        if (q == 0) {
            float4 o0, o1;
            o0.x = acc[0]; o0.y = acc[1]; o0.z = acc[2]; o0.w = acc[3];
            o1.x = acc[4]; o1.y = acc[5]; o1.z = acc[6]; o1.w = acc[7];
            *(float4*)(fout + (size_t)gw * 128 + ql * 8) = o0;
            *(float4*)(fout + (size_t)gw * 128 + ql * 8 + 4) = o1;
        }
    }
}

// W12 = W1 @ W2  (128x128 @ 128x128) f32, one output per thread.
__global__ void k_w12(const float* __restrict__ W1, const float* __restrict__ W2,
                      float* __restrict__ w12) {
    int idx = blockIdx.x * 256 + threadIdx.x;  // 0..16383
    int i = idx >> 7, j = idx & 127;
    float s = 0.f;
#pragma unroll 8
    for (int k = 0; k < 128; ++k) s = fmaf(W1[i * 128 + k], W2[k * 128 + j], s);
    w12[idx] = s;
}

// Pack W12 into MFMA B-fragment order, bf16 hi + lo residual.
// Fragment (nt, kb): lane l holds B[kb*32 + (l>>4)*8 + i][nt*16 + (l&15)],
// i = 0..7, stored as 16B at ((nt*4+kb)*64 + l)*16.
__global__ void k_wpack(const float* __restrict__ w12,
                        ushort* __restrict__ wph, ushort* __restrict__ wpl) {
    int idx = blockIdx.x * 256 + threadIdx.x;  // 0..2047
    int lane = idx & 63;
    int kb = (idx >> 6) & 3;
    int nt = idx >> 8;
    int n = nt * 16 + (lane & 15);
    int k0 = kb * 32 + (lane >> 4) * 8;
    ushort h[8], l[8];
#pragma unroll
    for (int i = 0; i < 8; ++i) {
        float f = w12[(k0 + i) * 128 + n];
        h[i] = bf16rn(f);
        l[i] = bf16rn(f - bf16tof(h[i]));
    }
    uint4 oh, ol;
    oh.x = (uint)h[0] | ((uint)h[1] << 16);
    oh.y = (uint)h[2] | ((uint)h[3] << 16);
    oh.z = (uint)h[4] | ((uint)h[5] << 16);
    oh.w = (uint)h[6] | ((uint)h[7] << 16);
    ol.x = (uint)l[0] | ((uint)l[1] << 16);
    ol.y = (uint)l[2] | ((uint)l[3] << 16);
    ol.z = (uint)l[4] | ((uint)l[5] << 16);
    ol.w = (uint)l[6] | ((uint)l[7] << 16);
    ((uint4*)wph)[idx] = oh;
    ((uint4*)wpl)[idx] = ol;
}

// cvec = b1^T @ W2  (128,)
__global__ void k_cvec(const float* __restrict__ b1, const float* __restrict__ W2,
                       float* __restrict__ cvec) {
    int j = threadIdx.x;
    float s = 0.f;
#pragma unroll 8
    for (int k = 0; k < 128; ++k) s = fmaf(b1[k], W2[k * 128 + j], s);
    cvec[j] = s;
}

// out = relu( X @ W12 + svec ⊗ cvec + b2 ) — MFMA bf16 split-precision.
// 256 threads / 4 waves; block covers 128 rows; wave owns 32 rows (2 strips
// of 16) x all 8 col-tiles. X read as f32, hi/lo bf16 built in-register.
// W fragments (hi+lo, 64KB) staged in LDS -> 2 blocks/CU.
// In-place safe (X == out): all A loads precede all stores within a block.
__launch_bounds__(256)
__global__ void k_gemm_mfma(const float* __restrict__ X,
                            const ushort* __restrict__ wph, const ushort* __restrict__ wpl,
                            const float* __restrict__ svec, const float* __restrict__ cvec,
                            const float* __restrict__ b2, float* __restrict__ out, int N) {
    __shared__ uint4 wsh[2048];  // 32 KB
    __shared__ uint4 wsl[2048];  // 32 KB
    int tid = threadIdx.x;
    int lane = tid & 63;
    int wv = tid >> 6;
    int row0 = blockIdx.x * 128;

    // stage packed W fragments
#pragma unroll
    for (int it = 0; it < 8; ++it) {
        wsh[it * 256 + tid] = ((const uint4*)wph)[it * 256 + tid];
        wsl[it * 256 + tid] = ((const uint4*)wpl)[it * 256 + tid];
    }

    // A fragments: strip s (16 rows), k-block kb (32 cols of K).
    // lane l: row = base + (l&15), k = kb*32 + (l>>4)*8 + i
    bf16x8 ah[2][4], al[2][4];
#pragma unroll
    for (int s = 0; s < 2; ++s) {
#pragma unroll
        for (int kb = 0; kb < 4; ++kb) {
            int row = row0 + wv * 32 + s * 16 + (lane & 15);
            int kbase = kb * 32 + (lane >> 4) * 8;
            float f[8];
            if (row < N) {
                float4 a = *(const float4*)(X + (size_t)row * 128 + kbase);
                float4 b = *(const float4*)(X + (size_t)row * 128 + kbase + 4);
                f[0] = a.x; f[1] = a.y; f[2] = a.z; f[3] = a.w;
                f[4] = b.x; f[5] = b.y; f[6] = b.z; f[7] = b.w;
            } else {
#pragma unroll
                for (int i = 0; i < 8; ++i) f[i] = 0.f;
            }
            bf16x8 hh, ll;
#pragma unroll
            for (int i = 0; i < 8; ++i) {
                ushort h = bf16rn(f[i]);
                hh[i] = (short)h;
                ll[i] = (short)bf16rn(f[i] - bf16tof(h));
            }
            ah[s][kb] = hh;
            al[s][kb] = ll;
        }
    }
    __syncthreads();

    f32x4 acc[2][8];
#pragma unroll
    for (int s = 0; s < 2; ++s)
#pragma unroll
        for (int nt = 0; nt < 8; ++nt) acc[s][nt] = (f32x4)(0.f);

#pragma unroll
    for (int nt = 0; nt < 8; ++nt) {
#pragma unroll
        for (int kb = 0; kb < 4; ++kb) {
            uint4 rh = wsh[(nt * 4 + kb) * 64 + lane];
            uint4 rl = wsl[(nt * 4 + kb) * 64 + lane];
            bf16x8 bh = __builtin_bit_cast(bf16x8, rh);
            bf16x8 bl = __builtin_bit_cast(bf16x8, rl);
            acc[0][nt] = __builtin_amdgcn_mfma_f32_16x16x32_bf16(ah[0][kb], bh, acc[0][nt], 0, 0, 0);
            acc[0][nt] = __builtin_amdgcn_mfma_f32_16x16x32_bf16(al[0][kb], bh, acc[0][nt], 0, 0, 0);
            acc[0][nt] = __builtin_amdgcn_mfma_f32_16x16x32_bf16(ah[0][kb], bl, acc[0][nt], 0, 0, 0);
            acc[1][nt] = __builtin_amdgcn_mfma_f32_16x16x32_bf16(ah[1][kb], bh, acc[1][nt], 0, 0, 0);
            acc[1][nt] = __builtin_amdgcn_mfma_f32_16x16x32_bf16(al[1][kb], bh, acc[1][nt], 0, 0, 0);
            acc[1][nt] = __builtin_amdgcn_mfma_f32_16x16x32_bf16(ah[1][kb], bl, acc[1][nt], 0, 0, 0);
        }
    }

    // epilogue: D elem r -> row_local = (lane>>4)*4 + r, col = nt*16 + (lane&15)
    float cv[8], bv[8];
#pragma unroll
    for (int nt = 0; nt < 8; ++nt) {
        cv[nt] = cvec[nt * 16 + (lane & 15)];
        bv[nt] = b2[nt * 16 + (lane & 15)];
    }
#pragma unroll
    for (int s = 0; s < 2; ++s) {
#pragma unroll
        for (int r = 0; r < 4; ++r) {
            int row = row0 + wv * 32 + s * 16 + (lane >> 4) * 4 + r;
            if (row < N) {
                float sv = svec[row];
#pragma unroll
                for (int nt = 0; nt < 8; ++nt) {
                    float o = fmaxf(acc[s][nt][r] + sv * cv[nt] + bv[nt], 0.f);
                    out[(size_t)row * 128 + nt * 16 + (lane & 15)] = o;
                }
            }
        }
    }
}

extern "C" void kernel_launch(void* const* d_in, const int* in_sizes, int n_in,
                              void* d_out, int out_size, void* d_ws, size_t ws_size,
                              hipStream_t stream) {
    const float* x  = (const float*)d_in[0];
    const int*   ei = (const int*)d_in[1];
    const float* W1 = (const float*)d_in[2];
    const float* b1 = (const float*)d_in[3];
    const float* W2 = (const float*)d_in[4];
    const float* b2 = (const float*)d_in[5];
    float* out = (float*)d_out;

    int N = in_sizes[0] / 128;
    int E = in_sizes[1] / 2;
    const int* srcE = ei;
    const int* dstE = ei + E;

    char* w = (char*)d_ws;
    size_t off = 0;
    auto alloc = [&](size_t bytes) {
        void* p = w + off;
        off = WS_ALIGN(off + bytes);
        return p;
    };
    ushort* xh    = (ushort*)alloc((size_t)N * 256);
    ushort* t1h   = (ushort*)alloc((size_t)N * 256);   // rank aliases here early
    int*   csr    = (int*)alloc((size_t)E * 4);
    int*   deg    = (int*)alloc((size_t)N * 4);
    int*   offs   = (int*)alloc((size_t)(N + 1) * 4);
    int*   bsums  = (int*)alloc(4096);
    float* dinv   = (float*)alloc((size_t)N * 4);
    float* svec   = (float*)alloc((size_t)N * 4);
    float* w12    = (float*)alloc(128 * 128 * 4);
    ushort* wph   = (ushort*)alloc(128 * 128 * 2);
    ushort* wpl   = (ushort*)alloc(128 * 128 * 2);
    float* cvec   = (float*)alloc(128 * 4);
    (void)ws_size; (void)n_in; (void)out_size;

    int nb = (N + 255) / 256;  // 391 for N=100000, fits k_scan2's 512
    int eb8 = (E + 8 * 256 - 1) / (8 * 256);
    int* rank = (int*)t1h;  // dead before t1h is written (stream-ordered)

    hipMemsetAsync(deg, 0, (size_t)N * 4, stream);
    k_rank<<<eb8, 256, 0, stream>>>(dstE, deg, rank, E, N);
    k_scan1<<<nb, 256, 0, stream>>>(deg, offs, bsums, dinv, N);
    k_scan2<<<1, 512, 0, stream>>>(bsums, nb);
    k_scan3<<<nb, 256, 0, stream>>>(offs, bsums, N, E);
    k_fill<<<eb8, 256, 0, stream>>>(srcE, dstE, rank, offs, csr, E, N);
    // convert x to f16 (rank is dead from here; t1h may be overwritten)
    k_tof16<<<2048, 256, 0, stream>>>(x, xh, N * 128 / 4);
    // pass 1: t1 = A x   (f16 in, f16 out) + svec = rowsum(A)
    k_aggq<1><<<(N + 3) / 4, 256, 0, stream>>>(xh, dinv, nullptr, t1h, svec,
                                               offs, csr, N);
    // pass 2: t2 = A t1  (f16 in, f32 out -> d_out as scratch)
    k_aggq<0><<<(N + 3) / 4, 256, 0, stream>>>(t1h, dinv, out, nullptr, nullptr,
                                               offs, csr, N);
    k_w12<<<64, 256, 0, stream>>>(W1, W2, w12);
    k_wpack<<<8, 256, 0, stream>>>(w12, wph, wpl);
    k_cvec<<<1, 128, 0, stream>>>(b1, W2, cvec);
    // out = relu(t2 @ W12 + svec ⊗ cvec + b2), MFMA, in-place on d_out
    k_gemm_mfma<<<(N + 127) / 128, 256, 0, stream>>>(out, wph, wpl, svec, cvec, b2, out, N);
}

// Round 11
// 282.639 us; speedup vs baseline: 1.4561x; 1.0508x over previous
//
#include <hip/hip_runtime.h>

// GCN 2-layer fused:  out = relu( A·(A·x)·(W1@W2) + (A·1)⊗(b1ᵀW2) + b2 )
// A = D^-1/2 (Adj + I) D^-1/2.  Both aggregation passes gather f16 rows;
// each wave processes TWO nodes with interleaved gather chains (latency
// overlap). tof16 rides inside k_rank (atomic-latency shadow); w12/cvec ride
// inside k_fill. Final GEMM: MFMA bf16 split-precision, in-place on d_out.
// All __shfl executed unconditionally (exec-masked ds_bpermute undefined).

#define WS_ALIGN(x) (((x) + 255) & ~(size_t)255)

typedef __attribute__((ext_vector_type(8))) short bf16x8;
typedef __attribute__((ext_vector_type(4))) float f32x4;
typedef _Float16 f16x8 __attribute__((ext_vector_type(8)));
typedef _Float16 f16x4 __attribute__((ext_vector_type(4)));

__device__ inline ushort bf16rn(float f) {
    uint u = __float_as_uint(f);
    u = (u + 0x7FFFu + ((u >> 16) & 1u)) >> 16;
    return (ushort)u;
}
__device__ inline float bf16tof(ushort h) {
    return __uint_as_float(((uint)h) << 16);
}

// blocks [0,rb): degree+rank (atomic-latency bound, ~0.5% VALU);
// blocks [rb,grid): x -> f16 conversion (streams in the latency shadow).
__global__ void k_rank_conv(const int* __restrict__ dst, int* __restrict__ deg,
                            int* __restrict__ rank, int E, int N,
                            const float* __restrict__ x, ushort* __restrict__ xh,
                            int n4, int rb) {
    if ((int)blockIdx.x < rb) {
        int tid = blockIdx.x * blockDim.x + threadIdx.x;
        int stride = rb * blockDim.x;
#pragma unroll
        for (int it = 0; it < 8; ++it) {
            int e = tid + it * stride;
            if (e < E) {
                int d = dst[e];
                if ((unsigned)d < (unsigned)N) rank[e] = atomicAdd(&deg[d], 1);
            }
        }
    } else {
        int tid = (blockIdx.x - rb) * blockDim.x + threadIdx.x;
        int stride = (gridDim.x - rb) * blockDim.x;
        for (int i = tid; i < n4; i += stride) {
            float4 v = ((const float4*)x)[i];
            f16x4 h;
            h[0] = (_Float16)v.x;
            h[1] = (_Float16)v.y;
            h[2] = (_Float16)v.z;
            h[3] = (_Float16)v.w;
            ((uint2*)xh)[i] = __builtin_bit_cast(uint2, h);
        }
    }
}

// Block-local exclusive scan of deg (256/block), emits block sums. Also
// computes dinv = rsqrt(deg+1) (self-loop).
__global__ void k_scan1(const int* __restrict__ deg, int* __restrict__ offs,
                        int* __restrict__ bsums, float* __restrict__ dinv, int N) {
    __shared__ int sh[256];
    int i = blockIdx.x * 256 + threadIdx.x;
    int v = (i < N) ? deg[i] : 0;
    if (i < N) dinv[i] = rsqrtf((float)(v + 1));
    sh[threadIdx.x] = v;
    __syncthreads();
    for (int off = 1; off < 256; off <<= 1) {
        int t = (threadIdx.x >= off) ? sh[threadIdx.x - off] : 0;
        __syncthreads();
        sh[threadIdx.x] += t;
        __syncthreads();
    }
    if (i < N) offs[i] = sh[threadIdx.x] - v;
    if (threadIdx.x == 255) bsums[blockIdx.x] = sh[255];
}

// Exclusive scan of up to 512 block sums in one block.
__global__ void k_scan2(int* __restrict__ bsums, int nb) {
    __shared__ int sh[512];
    int tid = threadIdx.x;
    int v = (tid < nb) ? bsums[tid] : 0;
    sh[tid] = v;
    __syncthreads();
    for (int off = 1; off < 512; off <<= 1) {
        int t = (tid >= off) ? sh[tid - off] : 0;
        __syncthreads();
        sh[tid] += t;
        __syncthreads();
    }
    if (tid < nb) bsums[tid] = sh[tid] - v;
}

__global__ void k_scan3(int* __restrict__ offs, const int* __restrict__ bsums, int N, int E) {
    int i = blockIdx.x * 256 + threadIdx.x;
    if (i < N) offs[i] += bsums[blockIdx.x];
    if (blockIdx.x == 0 && threadIdx.x == 0) offs[N] = E;
}

// blocks [0,fb): atomic-free CSR fill (slot = offs[dst] + rank);
// blocks [fb,fb+64): w12 = W1@W2; block fb+64: cvec = b1^T W2.
__global__ void k_fill_w12(const int* __restrict__ src, const int* __restrict__ dst,
                           const int* __restrict__ rank, const int* __restrict__ offs,
                           int* __restrict__ csr, int E, int N,
                           const float* __restrict__ W1, const float* __restrict__ b1,
                           const float* __restrict__ W2,
                           float* __restrict__ w12, float* __restrict__ cvec, int fb) {
    int bid = blockIdx.x;
    if (bid < fb) {
        int tid = bid * blockDim.x + threadIdx.x;
        int stride = fb * blockDim.x;
#pragma unroll
        for (int it = 0; it < 8; ++it) {
            int e = tid + it * stride;
            if (e < E) {
                int d = dst[e];
                int s = src[e];
                int r = rank[e];
                if ((unsigned)d < (unsigned)N && (unsigned)s < (unsigned)N)
                    csr[offs[d] + r] = s;
            }
        }
    } else if (bid < fb + 64) {
        int idx = (bid - fb) * 256 + threadIdx.x;  // 0..16383
        int i = idx >> 7, j = idx & 127;
        float s = 0.f;
#pragma unroll 8
        for (int k = 0; k < 128; ++k) s = fmaf(W1[i * 128 + k], W2[k * 128 + j], s);
        w12[idx] = s;
    } else {
        int j = threadIdx.x;
        if (j < 128) {
            float s = 0.f;
#pragma unroll 8
            for (int k = 0; k < 128; ++k) s = fmaf(b1[k], W2[k * 128 + j], s);
            cvec[j] = s;
        }
    }
}

// Aggregation over f16 rows, TWO nodes per wave (A = 2w, B = 2w+1): the two
// nodes' dependent chains (csr -> dinv -> bpermute -> row gather -> fma)
// interleave, hiding each other's latency. Quarter-wave (16 lanes) covers a
// 256B f16 row via uint4. Inner math compiles to v_fma_mix_f32.
// WRITE_Q=1: f16 rows out + svec = rowsum(A). WRITE_Q=0: f32 rows to fout.
template <int WRITE_Q>
__launch_bounds__(256)
__global__ void k_aggq(const ushort* __restrict__ xh, const float* __restrict__ dinv,
                       float* __restrict__ fout, ushort* __restrict__ qout,
                       float* __restrict__ svec,
                       const int* __restrict__ offs, const int* __restrict__ csr, int N) {
    int wid = (int)((blockIdx.x * (size_t)blockDim.x + threadIdx.x) >> 6);
    int lane = threadIdx.x & 63;
    int gwA = 2 * wid, gwB = 2 * wid + 1;
    if (gwA >= N) return;
    bool vB = (gwB < N);
    int q = lane >> 4, ql = lane & 15;
    float diA = dinv[gwA];
    float diB = vB ? dinv[gwB] : 0.f;
    const uint4* __restrict__ xh4 = (const uint4*)xh;

    float accA[8], accB[8];
#pragma unroll
    for (int j = 0; j < 8; ++j) { accA[j] = 0.f; accB[j] = 0.f; }
    float ssA = (lane == 0) ? diA : 0.f;
    float ssB = (lane == 0) ? diB : 0.f;

    if (q == 0) {  // self terms
        uint4 va = xh4[((size_t)gwA << 4) + ql];
        f16x8 ha = __builtin_bit_cast(f16x8, va);
#pragma unroll
        for (int j = 0; j < 8; ++j) accA[j] = diA * (float)ha[j];
        if (vB) {
            uint4 vb = xh4[((size_t)gwB << 4) + ql];
            f16x8 hb = __builtin_bit_cast(f16x8, vb);
#pragma unroll
            for (int j = 0; j < 8; ++j) accB[j] = diB * (float)hb[j];
        }
    }

    // offs contiguity: offs[gwB] == offs[gwA+1]
    int s0A = offs[gwA], s1A = offs[gwA + 1];
    int s0B = s1A, s1B = vB ? offs[gwB + 2 - 1 + 0 + 0] : s1A;  // offs[gwB+1]
    if (vB) s1B = offs[gwB + 1];

    int baseA = s0A, baseB = s0B;
    while (baseA < s1A || baseB < s1B) {
        int cA = s1A - baseA; cA = cA < 0 ? 0 : (cA > 64 ? 64 : cA);
        int cB = s1B - baseB; cB = cB < 0 ? 0 : (cB > 64 ? 64 : cB);
        int sidxA = 0, sidxB = 0;
        float dvA = 0.f, dvB = 0.f;   // padded lanes keep 0 -> contribute 0
        if (lane < cA) {
            sidxA = csr[baseA + lane];
            dvA = dinv[sidxA];
        }
        if (lane < cB) {
            sidxB = csr[baseB + lane];
            dvB = dinv[sidxB];
        }
        int itA = (cA + 3) >> 2, itB = (cB + 3) >> 2;
        int iters = itA > itB ? itA : itB;
#pragma unroll 2
        for (int i = 0; i < iters; ++i) {
            int t = 4 * i + q;   // t <= 63 always
            // shfls outside divergent guards (all source lanes active)
            int sA = __shfl(sidxA, t);
            float dA = __shfl(dvA, t);
            int sB = __shfl(sidxB, t);
            float dB = __shfl(dvB, t);
            if (t < cA) {
                uint4 v = xh4[((size_t)sA << 4) + ql];
                f16x8 h = __builtin_bit_cast(f16x8, v);
#pragma unroll
                for (int j = 0; j < 8; ++j) accA[j] = fmaf(dA, (float)h[j], accA[j]);
                if (WRITE_Q && ql == 0) ssA += dA;
            }
            if (t < cB) {
                uint4 v = xh4[((size_t)sB << 4) + ql];
                f16x8 h = __builtin_bit_cast(f16x8, v);
#pragma unroll
                for (int j = 0; j < 8; ++j) accB[j] = fmaf(dB, (float)h[j], accB[j]);
                if (WRITE_Q && ql == 0) ssB += dB;
            }
        }
        baseA += 64;
        baseB += 64;
    }

    // butterfly combine: every lane ends with the full sum of its slice
#pragma unroll
    for (int j = 0; j < 8; ++j) {
        accA[j] += __shfl_xor(accA[j], 16);
        accA[j] += __shfl_xor(accA[j], 32);
        accA[j] *= diA;
        accB[j] += __shfl_xor(accB[j], 16);
        accB[j] += __shfl_xor(accB[j], 32);
        accB[j] *= diB;
    }

    if (WRITE_Q) {
        ssA += __shfl_xor(ssA, 16);
        ssA += __shfl_xor(ssA, 32);
        ssB += __shfl_xor(ssB, 16);
        ssB += __shfl_xor(ssB, 32);
        if (lane == 0) {
            svec[gwA] = diA * ssA;
            if (vB) svec[gwB] = diB * ssB;
        }
        if (q == 0) {
            f16x8 ha, hb;
#pragma unroll
            for (int j = 0; j < 8; ++j) { ha[j] = (_Float16)accA[j]; hb[j] = (_Float16)accB[j]; }
            *(uint4*)(qout + (size_t)gwA * 128 + ql * 8) = __builtin_bit_cast(uint4, ha);
            if (vB) *(uint4*)(qout + (size_t)gwB * 128 + ql * 8) = __builtin_bit_cast(uint4, hb);
        }
    } else {
        if (q == 0) {
            float4 o0, o1;
            o0.x = accA[0]; o0.y = accA[1]; o0.z = accA[2]; o0.w = accA[3];
            o1.x = accA[4]; o1.y = accA[5]; o1.z = accA[6]; o1.w = accA[7];
            *(float4*)(fout + (size_t)gwA * 128 + ql * 8) = o0;
            *(float4*)(fout + (size_t)gwA * 128 + ql * 8 + 4) = o1;
            if (vB) {
                float4 p0, p1;
                p0.x = accB[0]; p0.y = accB[1]; p0.z = accB[2]; p0.w = accB[3];
                p1.x = accB[4]; p1.y = accB[5]; p1.z = accB[6]; p1.w = accB[7];
                *(float4*)(fout + (size_t)gwB * 128 + ql * 8) = p0;
                *(float4*)(fout + (size_t)gwB * 128 + ql * 8 + 4) = p1;
            }
        }
    }
}

// Pack W12 into MFMA B-fragment order, bf16 hi + lo residual.
// Fragment (nt, kb): lane l holds B[kb*32 + (l>>4)*8 + i][nt*16 + (l&15)],
// i = 0..7, stored as 16B at ((nt*4+kb)*64 + l)*16.
__global__ void k_wpack(const float* __restrict__ w12,
                        ushort* __restrict__ wph, ushort* __restrict__ wpl) {
    int idx = blockIdx.x * 256 + threadIdx.x;  // 0..2047
    int lane = idx & 63;
    int kb = (idx >> 6) & 3;
    int nt = idx >> 8;
    int n = nt * 16 + (lane & 15);
    int k0 = kb * 32 + (lane >> 4) * 8;
    ushort h[8], l[8];
#pragma unroll
    for (int i = 0; i < 8; ++i) {
        float f = w12[(k0 + i) * 128 + n];
        h[i] = bf16rn(f);
        l[i] = bf16rn(f - bf16tof(h[i]));
    }
    uint4 oh, ol;
    oh.x = (uint)h[0] | ((uint)h[1] << 16);
    oh.y = (uint)h[2] | ((uint)h[3] << 16);
    oh.z = (uint)h[4] | ((uint)h[5] << 16);
    oh.w = (uint)h[6] | ((uint)h[7] << 16);
    ol.x = (uint)l[0] | ((uint)l[1] << 16);
    ol.y = (uint)l[2] | ((uint)l[3] << 16);
    ol.z = (uint)l[4] | ((uint)l[5] << 16);
    ol.w = (uint)l[6] | ((uint)l[7] << 16);
    ((uint4*)wph)[idx] = oh;
    ((uint4*)wpl)[idx] = ol;
}

// out = relu( X @ W12 + svec ⊗ cvec + b2 ) — MFMA bf16 split-precision
// (X@W = Xhi·Whi + Xlo·Whi + Xhi·Wlo). 256 threads / 4 waves; block covers
// 128 rows; wave owns 32 rows x all 8 col-tiles. W fragments in LDS (64KB).
// In-place safe (X == out): all A loads precede all stores within a block.
__launch_bounds__(256)
__global__ void k_gemm_mfma(const float* __restrict__ X,
                            const ushort* __restrict__ wph, const ushort* __restrict__ wpl,
                            const float* __restrict__ svec, const float* __restrict__ cvec,
                            const float* __restrict__ b2, float* __restrict__ out, int N) {
    __shared__ uint4 wsh[2048];  // 32 KB
    __shared__ uint4 wsl[2048];  // 32 KB
    int tid = threadIdx.x;
    int lane = tid & 63;
    int wv = tid >> 6;
    int row0 = blockIdx.x * 128;

#pragma unroll
    for (int it = 0; it < 8; ++it) {
        wsh[it * 256 + tid] = ((const uint4*)wph)[it * 256 + tid];
        wsl[it * 256 + tid] = ((const uint4*)wpl)[it * 256 + tid];
    }

    // A fragments: strip s (16 rows), k-block kb. lane l: row = base+(l&15),
    // k = kb*32 + (l>>4)*8 + i
    bf16x8 ah[2][4], al[2][4];
#pragma unroll
    for (int s = 0; s < 2; ++s) {
#pragma unroll
        for (int kb = 0; kb < 4; ++kb) {
            int row = row0 + wv * 32 + s * 16 + (lane & 15);
            int kbase = kb * 32 + (lane >> 4) * 8;
            float f[8];
            if (row < N) {
                float4 a = *(const float4*)(X + (size_t)row * 128 + kbase);
                float4 b = *(const float4*)(X + (size_t)row * 128 + kbase + 4);
                f[0] = a.x; f[1] = a.y; f[2] = a.z; f[3] = a.w;
                f[4] = b.x; f[5] = b.y; f[6] = b.z; f[7] = b.w;
            } else {
#pragma unroll
                for (int i = 0; i < 8; ++i) f[i] = 0.f;
            }
            bf16x8 hh, ll;
#pragma unroll
            for (int i = 0; i < 8; ++i) {
                ushort h = bf16rn(f[i]);
                hh[i] = (short)h;
                ll[i] = (short)bf16rn(f[i] - bf16tof(h));
            }
            ah[s][kb] = hh;
            al[s][kb] = ll;
        }
    }
    __syncthreads();

    f32x4 acc[2][8];
#pragma unroll
    for (int s = 0; s < 2; ++s)
#pragma unroll
        for (int nt = 0; nt < 8; ++nt) acc[s][nt] = (f32x4)(0.f);

#pragma unroll
    for (int nt = 0; nt < 8; ++nt) {
#pragma unroll
        for (int kb = 0; kb < 4; ++kb) {
            uint4 rh = wsh[(nt * 4 + kb) * 64 + lane];
            uint4 rl = wsl[(nt * 4 + kb) * 64 + lane];
            bf16x8 bh = __builtin_bit_cast(bf16x8, rh);
            bf16x8 bl = __builtin_bit_cast(bf16x8, rl);
            acc[0][nt] = __builtin_amdgcn_mfma_f32_16x16x32_bf16(ah[0][kb], bh, acc[0][nt], 0, 0, 0);
            acc[0][nt] = __builtin_amdgcn_mfma_f32_16x16x32_bf16(al[0][kb], bh, acc[0][nt], 0, 0, 0);
            acc[0][nt] = __builtin_amdgcn_mfma_f32_16x16x32_bf16(ah[0][kb], bl, acc[0][nt], 0, 0, 0);
            acc[1][nt] = __builtin_amdgcn_mfma_f32_16x16x32_bf16(ah[1][kb], bh, acc[1][nt], 0, 0, 0);
            acc[1][nt] = __builtin_amdgcn_mfma_f32_16x16x32_bf16(al[1][kb], bh, acc[1][nt], 0, 0, 0);
            acc[1][nt] = __builtin_amdgcn_mfma_f32_16x16x32_bf16(ah[1][kb], bl, acc[1][nt], 0, 0, 0);
        }
    }

    float cv[8], bv[8];
#pragma unroll
    for (int nt = 0; nt < 8; ++nt) {
        cv[nt] = cvec[nt * 16 + (lane & 15)];
        bv[nt] = b2[nt * 16 + (lane & 15)];
    }
#pragma unroll
    for (int s = 0; s < 2; ++s) {
#pragma unroll
        for (int r = 0; r < 4; ++r) {
            int row = row0 + wv * 32 + s * 16 + (lane >> 4) * 4 + r;
            if (row < N) {
                float sv = svec[row];
#pragma unroll
                for (int nt = 0; nt < 8; ++nt) {
                    float o = fmaxf(acc[s][nt][r] + sv * cv[nt] + bv[nt], 0.f);
                    out[(size_t)row * 128 + nt * 16 + (lane & 15)] = o;
                }
            }
        }
    }
}

extern "C" void kernel_launch(void* const* d_in, const int* in_sizes, int n_in,
                              void* d_out, int out_size, void* d_ws, size_t ws_size,
                              hipStream_t stream) {
    const float* x  = (const float*)d_in[0];
    const int*   ei = (const int*)d_in[1];
    const float* W1 = (const float*)d_in[2];
    const float* b1 = (const float*)d_in[3];
    const float* W2 = (const float*)d_in[4];
    const float* b2 = (const float*)d_in[5];
    float* out = (float*)d_out;

    int N = in_sizes[0] / 128;
    int E = in_sizes[1] / 2;
    const int* srcE = ei;
    const int* dstE = ei + E;

    char* w = (char*)d_ws;
    size_t off = 0;
    auto alloc = [&](size_t bytes) {
        void* p = w + off;
        off = WS_ALIGN(off + bytes);
        return p;
    };
    ushort* xh    = (ushort*)alloc((size_t)N * 256);
    ushort* t1h   = (ushort*)alloc((size_t)N * 256);   // rank aliases here early
    int*   csr    = (int*)alloc((size_t)E * 4);
    int*   deg    = (int*)alloc((size_t)N * 4);
    int*   offs   = (int*)alloc((size_t)(N + 1) * 4);
    int*   bsums  = (int*)alloc(4096);
    float* dinv   = (float*)alloc((size_t)N * 4);
    float* svec   = (float*)alloc((size_t)N * 4);
    float* w12    = (float*)alloc(128 * 128 * 4);
    ushort* wph   = (ushort*)alloc(128 * 128 * 2);
    ushort* wpl   = (ushort*)alloc(128 * 128 * 2);
    float* cvec   = (float*)alloc(128 * 4);
    (void)ws_size; (void)n_in; (void)out_size;

    int nb = (N + 255) / 256;  // 391 for N=100000, fits k_scan2's 512
    int eb8 = (E + 8 * 256 - 1) / (8 * 256);
    int* rank = (int*)t1h;  // dead before t1h is written (stream-ordered)

    hipMemsetAsync(deg, 0, (size_t)N * 4, stream);
    // rank (atomic wall) with x->f16 conversion riding in its latency shadow
    k_rank_conv<<<eb8 + 1024, 256, 0, stream>>>(dstE, deg, rank, E, N,
                                                x, xh, N * 128 / 4, eb8);
    k_scan1<<<nb, 256, 0, stream>>>(deg, offs, bsums, dinv, N);
    k_scan2<<<1, 512, 0, stream>>>(bsums, nb);
    k_scan3<<<nb, 256, 0, stream>>>(offs, bsums, N, E);
    // CSR fill with w12 / cvec riding along as extra blocks
    k_fill_w12<<<eb8 + 65, 256, 0, stream>>>(srcE, dstE, rank, offs, csr, E, N,
                                             W1, b1, W2, w12, cvec, eb8);
    // pass 1: t1 = A x   (f16 in, f16 out) + svec = rowsum(A)
    k_aggq<1><<<(N + 7) / 8, 256, 0, stream>>>(xh, dinv, nullptr, t1h, svec,
                                               offs, csr, N);
    // pass 2: t2 = A t1  (f16 in, f32 out -> d_out as scratch)
    k_aggq<0><<<(N + 7) / 8, 256, 0, stream>>>(t1h, dinv, out, nullptr, nullptr,
                                               offs, csr, N);
    k_wpack<<<8, 256, 0, stream>>>(w12, wph, wpl);
    // out = relu(t2 @ W12 + svec ⊗ cvec + b2), MFMA, in-place on d_out
    k_gemm_mfma<<<(N + 127) / 128, 256, 0, stream>>>(out, wph, wpl, svec, cvec, b2, out, N);
}